// Round 1
// baseline (14244.397 us; speedup 1.0000x reference)
//
#include <hip/hip_runtime.h>
#include <cstddef>
#include <cstdint>

// Problem constants
#define BDIM  1024        // batch rows
#define DM    512         // embedding dim
#define CREAL 10000       // dictionary atoms
#define CP    10112       // padded atoms = 79*128 = 316*32
#define KSPL  16          // split-K chunks for GEMM1
#define RHOC  5.0f
#define THRC  (0.01f/5.0f)
#define NIT   100
#define NSIT  12

typedef float f32x4 __attribute__((ext_vector_type(4)));
typedef _Float16 f16x8 __attribute__((ext_vector_type(8)));
typedef _Float16 f16x4 __attribute__((ext_vector_type(4)));
typedef unsigned int u32x4 __attribute__((ext_vector_type(4)));

// ---------------- helpers ----------------

// Pair scheme: x ~ h + l/64, h=fp16(x), l=fp16((x-h)*64). GEMM uses 3 terms:
// h*h + (h*2^-6)*l + l*(h*2^-6)  (l*l dropped, ~2^-24 rel).
__device__ __forceinline__ f16x8 scl6(f16x8 v) {
    f16x8 r;
#pragma unroll
    for (int i = 0; i < 8; i++) r[i] = v[i] * (_Float16)0.015625f;  // exact exponent shift
    return r;
}

// |s| on an (h,l) pair is EXACT: flip both signs where h is negative.
__device__ __forceinline__ void absfold(f16x8& h8, f16x8& l8) {
    u32x4 h = __builtin_bit_cast(u32x4, h8);
    u32x4 l = __builtin_bit_cast(u32x4, l8);
    u32x4 m = h & 0x80008000u;
    h8 = __builtin_bit_cast(f16x8, h ^ m);
    l8 = __builtin_bit_cast(f16x8, l ^ m);
}

// relu(s) on an (h,l) pair: zero both where h<=0 (edge err ~2^-24, negligible).
__device__ __forceinline__ void relufold(f16x8& h8, f16x8& l8) {
#pragma unroll
    for (int e = 0; e < 8; e++) {
        bool p = h8[e] > (_Float16)0;
        if (!p) { h8[e] = (_Float16)0; l8[e] = (_Float16)0; }
    }
}

// fragment-swizzled plane index for an A-operand matrix [rows][C]:
//   idx = ((row>>4)*(C>>5) + (col>>5))*512 + (((col>>3)&3)*16 + (row&15))*8 + (col&7)
// so a wave's fragment load for (rowtile, coltile32) is base + lane*8.
__device__ __forceinline__ size_t psidx(int row, int col) {   // C = CP (s-planes)
    return ((size_t)(row >> 4) * (CP >> 5) + (size_t)(col >> 5)) * 512
         + (size_t)((((col >> 3) & 3) * 16 + (row & 15)) * 8 + (col & 7));
}

__device__ __forceinline__ float blk_sum256(float v) {
    __shared__ float sb[4];
#pragma unroll
    for (int o = 32; o; o >>= 1) v += __shfl_down(v, o, 64);
    int lane = threadIdx.x & 63, w = threadIdx.x >> 6;
    __syncthreads();
    if (lane == 0) sb[w] = v;
    __syncthreads();
    return sb[0] + sb[1] + sb[2] + sb[3];
}

// txt = normalize(text) per row
__global__ __launch_bounds__(256) void knorm_rows(const float* __restrict__ X,
                                                  float* __restrict__ out) {
    int row = blockIdx.x, t = threadIdx.x;
    int off = row * DM + t * 2;
    float2 v = *(const float2*)(X + off);
    float ss = blk_sum256(v.x * v.x + v.y * v.y);
    float inv = 1.0f / fmaxf(sqrtf(ss), 1e-12f);
    float2 o = {v.x * inv, v.y * inv};
    *(float2*)(out + off) = o;
}

// Y = normalize(normalize(image) - mean) per row
__global__ __launch_bounds__(256) void kprep_Y(const float* __restrict__ img,
                                               const float* __restrict__ mean,
                                               float* __restrict__ Y) {
    int row = blockIdx.x, t = threadIdx.x;
    int off = row * DM + t * 2;
    float2 v = *(const float2*)(img + off);
    float ss = blk_sum256(v.x * v.x + v.y * v.y);
    float inv = 1.0f / fmaxf(sqrtf(ss), 1e-12f);
    float2 mm = *(const float2*)(mean + t * 2);
    float tx = v.x * inv - mm.x, ty = v.y * inv - mm.y;
    float ss2 = blk_sum256(tx * tx + ty * ty);
    float inv2 = 1.0f / fmaxf(sqrtf(ss2), 1e-12f);
    float2 o = {tx * inv2, ty * inv2};
    *(float2*)(Y + off) = o;
}

// transpose (+zero-pad rows>=Rvalid), split to fp16 h/l pair (l stored *64) and write
// the fp16 planes in MFMA FRAGMENT-SWIZZLED order (see psidx formula).
// optional fp32 out = reconstructed pair, ROW-MAJOR.
__global__ __launch_bounds__(256) void ktrs(const float* __restrict__ in,
                                            float* __restrict__ out32,
                                            _Float16* __restrict__ oH,
                                            _Float16* __restrict__ oL,
                                            int Rvalid, int Cin, int Rout) {
    __shared__ float tile[64][65];
    int r0 = blockIdx.x * 64;   // rows of in  (cols of out)
    int c0 = blockIdx.y * 64;   // cols of in  (rows of out)
    int t = threadIdx.x;
    int ri = r0 + (t >> 2);
    int cc = (t & 3) * 16;
#pragma unroll
    for (int q = 0; q < 4; ++q) {
        float4 v = {0.f, 0.f, 0.f, 0.f};
        if (ri < Rvalid) v = *(const float4*)(in + (size_t)ri * Cin + c0 + cc + q * 4);
        *(float4*)&tile[t >> 2][cc + q * 4] = v;
    }
    __syncthreads();
    int oc = c0 + (t >> 2);            // out row
    int orr = r0 + (t & 3) * 16;       // out col base (multiple of 16)
    _Float16 hv[16], lv[16];
#pragma unroll
    for (int q = 0; q < 16; ++q) {
        float v = tile[(t & 3) * 16 + q][t >> 2];
        _Float16 h = (_Float16)v;
        _Float16 l = (_Float16)((v - (float)h) * 64.f);
        hv[q] = h; lv[q] = l;
        if (out32) out32[(size_t)oc * Rout + orr + q] = (float)h + (float)l * 0.015625f;
    }
    int rt = oc >> 4, rin = oc & 15;
    int kt = orr >> 5;
    int kq0 = (orr >> 3) & 3;          // 0 or 2
    size_t base = ((size_t)rt * (Rout >> 5) + kt) * 512;
    *(f16x8*)(oH + base + (size_t)(kq0 * 16 + rin) * 8)       = *(f16x8*)&hv[0];
    *(f16x8*)(oH + base + (size_t)((kq0 + 1) * 16 + rin) * 8) = *(f16x8*)&hv[8];
    *(f16x8*)(oL + base + (size_t)(kq0 * 16 + rin) * 8)       = *(f16x8*)&lv[0];
    *(f16x8*)(oL + base + (size_t)((kq0 + 1) * 16 + rin) * 8) = *(f16x8*)&lv[8];
}

// csum[n] = sum_k Dt[n][k]  (deterministic per-row wave reduce)
__global__ void kcsum(const float* __restrict__ Dt, float* __restrict__ csum) {
    int n = blockIdx.x, t = threadIdx.x;   // 64 threads = 1 wave
    float s = 0.f;
    for (int k = t; k < CP; k += 64) s += Dt[(size_t)n * CP + k];
#pragma unroll
    for (int o = 32; o; o >>= 1) s += __shfl_down(s, o, 64);
    if (t == 0) csum[n] = s;
}

// G = Dt*Dt^T + rho I  (Dt [512][CP] fp32; 64x64 tiles, K=CP)
__global__ __launch_bounds__(256) void kG(const float* __restrict__ Dt,
                                          float* __restrict__ G) {
    __shared__ float As[32][68];
    __shared__ float Bs[32][68];
    int tid = threadIdx.x;
    int j0 = blockIdx.x * 64, i0 = blockIdx.y * 64;
    int tn = (tid & 15) * 4, tm = (tid >> 4) * 4;
    float acc[4][4];
#pragma unroll
    for (int i = 0; i < 4; i++)
#pragma unroll
        for (int j = 0; j < 4; j++) acc[i][j] = 0.f;
    for (int k0 = 0; k0 < CP; k0 += 32) {
        __syncthreads();
#pragma unroll
        for (int p = 0; p < 2; ++p) {
            int idx = tid + p * 256;
            int row = idx >> 3, kv = (idx & 7) << 2;
            float4 va = *(const float4*)(Dt + (size_t)(i0 + row) * CP + k0 + kv);
            As[kv + 0][row] = va.x; As[kv + 1][row] = va.y;
            As[kv + 2][row] = va.z; As[kv + 3][row] = va.w;
            float4 vb = *(const float4*)(Dt + (size_t)(j0 + row) * CP + k0 + kv);
            Bs[kv + 0][row] = vb.x; Bs[kv + 1][row] = vb.y;
            Bs[kv + 2][row] = vb.z; Bs[kv + 3][row] = vb.w;
        }
        __syncthreads();
#pragma unroll
        for (int k = 0; k < 32; ++k) {
            float4 a4 = *(const float4*)&As[k][tm];
            float4 b4 = *(const float4*)&Bs[k][tn];
            float af[4] = {a4.x, a4.y, a4.z, a4.w};
            float bf[4] = {b4.x, b4.y, b4.z, b4.w};
#pragma unroll
            for (int i = 0; i < 4; i++)
#pragma unroll
                for (int j = 0; j < 4; j++) acc[i][j] = fmaf(af[i], bf[j], acc[i][j]);
        }
    }
#pragma unroll
    for (int i = 0; i < 4; i++)
#pragma unroll
        for (int j = 0; j < 4; j++) {
            int gi = i0 + tm + i, gj = j0 + tn + j;
            G[gi * DM + gj] = acc[i][j] + ((gi == gj) ? RHOC : 0.f);
        }
}

__global__ void krow_abssum(const float* __restrict__ G, float* __restrict__ gmax) {
    int row = blockIdx.x, t = threadIdx.x;   // 64 threads = 1 wave
    float s = 0.f;
    for (int j = t; j < DM; j += 64) s += fabsf(G[row * DM + j]);
#pragma unroll
    for (int o = 32; o; o >>= 1) s += __shfl_down(s, o, 64);
    if (t == 0) atomicMax((int*)gmax, __float_as_int(s));
}

__global__ void kinit_X0(const float* __restrict__ gmax, float* __restrict__ X) {
    int idx = blockIdx.x * 256 + threadIdx.x;
    int i = idx >> 9, j = idx & 511;
    X[idx] = (i == j) ? (1.0f / gmax[0]) : 0.0f;
}

// T = G @ X (512^3 NN, 64x64 tiles)
__global__ __launch_bounds__(256) void kgemm_ns_T(const float* __restrict__ G,
                                                  const float* __restrict__ X,
                                                  float* __restrict__ T) {
    __shared__ float As[32][68];
    __shared__ float Bs[32][68];
    int tid = threadIdx.x;
    int n0 = blockIdx.x * 64, m0 = blockIdx.y * 64;
    int tn = (tid & 15) * 4, tm = (tid >> 4) * 4;
    float acc[4][4];
#pragma unroll
    for (int i = 0; i < 4; i++)
#pragma unroll
        for (int j = 0; j < 4; j++) acc[i][j] = 0.f;
    for (int k0 = 0; k0 < DM; k0 += 32) {
        __syncthreads();
#pragma unroll
        for (int p = 0; p < 2; ++p) {
            int idx = tid + p * 256;
            {
                int row = idx >> 3, kv = (idx & 7) << 2;
                float4 v = *(const float4*)(G + (m0 + row) * DM + k0 + kv);
                As[kv + 0][row] = v.x; As[kv + 1][row] = v.y;
                As[kv + 2][row] = v.z; As[kv + 3][row] = v.w;
            }
            {
                int r = idx >> 4, cv = (idx & 15) << 2;
                *(float4*)&Bs[r][cv] = *(const float4*)(X + (k0 + r) * DM + n0 + cv);
            }
        }
        __syncthreads();
#pragma unroll
        for (int k = 0; k < 32; ++k) {
            float4 a4 = *(const float4*)&As[k][tm];
            float4 b4 = *(const float4*)&Bs[k][tn];
            float af[4] = {a4.x, a4.y, a4.z, a4.w};
            float bf[4] = {b4.x, b4.y, b4.z, b4.w};
#pragma unroll
            for (int i = 0; i < 4; i++)
#pragma unroll
                for (int j = 0; j < 4; j++) acc[i][j] = fmaf(af[i], bf[j], acc[i][j]);
        }
    }
#pragma unroll
    for (int i = 0; i < 4; i++) {
        float4 o = {acc[i][0], acc[i][1], acc[i][2], acc[i][3]};
        *(float4*)(T + (m0 + tm + i) * DM + n0 + tn) = o;
    }
}

// Xn = 2*Xo - Xo @ T
__global__ __launch_bounds__(256) void kgemm_ns_X(const float* __restrict__ Xo,
                                                  const float* __restrict__ T,
                                                  float* __restrict__ Xn) {
    __shared__ float As[32][68];
    __shared__ float Bs[32][68];
    int tid = threadIdx.x;
    int n0 = blockIdx.x * 64, m0 = blockIdx.y * 64;
    int tn = (tid & 15) * 4, tm = (tid >> 4) * 4;
    float acc[4][4];
#pragma unroll
    for (int i = 0; i < 4; i++)
#pragma unroll
        for (int j = 0; j < 4; j++) acc[i][j] = 0.f;
    for (int k0 = 0; k0 < DM; k0 += 32) {
        __syncthreads();
#pragma unroll
        for (int p = 0; p < 2; ++p) {
            int idx = tid + p * 256;
            {
                int row = idx >> 3, kv = (idx & 7) << 2;
                float4 v = *(const float4*)(Xo + (m0 + row) * DM + k0 + kv);
                As[kv + 0][row] = v.x; As[kv + 1][row] = v.y;
                As[kv + 2][row] = v.z; As[kv + 3][row] = v.w;
            }
            {
                int r = idx >> 4, cv = (idx & 15) << 2;
                *(float4*)&Bs[r][cv] = *(const float4*)(T + (k0 + r) * DM + n0 + cv);
            }
        }
        __syncthreads();
#pragma unroll
        for (int k = 0; k < 32; ++k) {
            float4 a4 = *(const float4*)&As[k][tm];
            float4 b4 = *(const float4*)&Bs[k][tn];
            float af[4] = {a4.x, a4.y, a4.z, a4.w};
            float bf[4] = {b4.x, b4.y, b4.z, b4.w};
#pragma unroll
            for (int i = 0; i < 4; i++)
#pragma unroll
                for (int j = 0; j < 4; j++) acc[i][j] = fmaf(af[i], bf[j], acc[i][j]);
        }
    }
#pragma unroll
    for (int i = 0; i < 4; i++) {
        int base = (m0 + tm + i) * DM + n0 + tn;
        float4 xo = *(const float4*)(Xo + base);
        float4 o = {2.f * xo.x - acc[i][0], 2.f * xo.y - acc[i][1],
                    2.f * xo.z - acc[i][2], 2.f * xo.w - acc[i][3]};
        *(float4*)(Xn + base) = o;
    }
}

// NN fp32: out[M][CP] = A[M][512] @ B[512][CP]
// MODE 0: store fp32. MODE 1: store a = acc*0.2 as fp16 scaled by 64.
template <int MODE>
__global__ __launch_bounds__(256) void kgemm_nn64(const float* __restrict__ A,
                                                  const float* __restrict__ B,
                                                  float* __restrict__ out32,
                                                  _Float16* __restrict__ oA) {
    __shared__ float As[32][68];
    __shared__ float Bs[32][68];
    int tid = threadIdx.x;
    int n0 = blockIdx.x * 64, m0 = blockIdx.y * 64;
    int tn = (tid & 15) * 4, tm = (tid >> 4) * 4;
    float acc[4][4];
#pragma unroll
    for (int i = 0; i < 4; i++)
#pragma unroll
        for (int j = 0; j < 4; j++) acc[i][j] = 0.f;
    for (int k0 = 0; k0 < DM; k0 += 32) {
        __syncthreads();
#pragma unroll
        for (int p = 0; p < 2; ++p) {
            int idx = tid + p * 256;
            {
                int row = idx >> 3, kv = (idx & 7) << 2;
                float4 v = *(const float4*)(A + (size_t)(m0 + row) * DM + k0 + kv);
                As[kv + 0][row] = v.x; As[kv + 1][row] = v.y;
                As[kv + 2][row] = v.z; As[kv + 3][row] = v.w;
            }
            {
                int r = idx >> 4, cv = (idx & 15) << 2;
                *(float4*)&Bs[r][cv] = *(const float4*)(B + (size_t)(k0 + r) * CP + n0 + cv);
            }
        }
        __syncthreads();
#pragma unroll
        for (int k = 0; k < 32; ++k) {
            float4 a4 = *(const float4*)&As[k][tm];
            float4 b4 = *(const float4*)&Bs[k][tn];
            float af[4] = {a4.x, a4.y, a4.z, a4.w};
            float bf[4] = {b4.x, b4.y, b4.z, b4.w};
#pragma unroll
            for (int i = 0; i < 4; i++)
#pragma unroll
                for (int j = 0; j < 4; j++) acc[i][j] = fmaf(af[i], bf[j], acc[i][j]);
        }
    }
#pragma unroll
    for (int i = 0; i < 4; i++)
#pragma unroll
        for (int j = 0; j < 4; j++) {
            size_t idx = (size_t)(m0 + tm + i) * CP + n0 + tn + j;
            if (MODE == 0) out32[idx] = acc[i][j];
            else           oA[idx] = (_Float16)(acc[i][j] * 0.2f * 64.f);
        }
}

// aD = Y@G/rho - Y - thr*csum   (out [1024][512]; 64x64 tiles, K=512)
// the -thr*csum term folds GEMM1's constant correction: v = |s| - thr.
__global__ __launch_bounds__(256) void kgemm_aD(const float* __restrict__ Yb,
                                                const float* __restrict__ G,
                                                const float* __restrict__ csum,
                                                float* __restrict__ aD) {
    __shared__ float As[32][68];
    __shared__ float Bs[32][68];
    int tid = threadIdx.x;
    int n0 = blockIdx.x * 64, m0 = blockIdx.y * 64;
    int tn = (tid & 15) * 4, tm = (tid >> 4) * 4;
    float acc[4][4];
#pragma unroll
    for (int i = 0; i < 4; i++)
#pragma unroll
        for (int j = 0; j < 4; j++) acc[i][j] = 0.f;
    for (int k0 = 0; k0 < DM; k0 += 32) {
        __syncthreads();
#pragma unroll
        for (int p = 0; p < 2; ++p) {
            int idx = tid + p * 256;
            {
                int row = idx >> 3, kv = (idx & 7) << 2;
                float4 v = *(const float4*)(Yb + (size_t)(m0 + row) * DM + k0 + kv);
                As[kv + 0][row] = v.x; As[kv + 1][row] = v.y;
                As[kv + 2][row] = v.z; As[kv + 3][row] = v.w;
            }
            {
                int r = idx >> 4, cv = (idx & 15) << 2;
                *(float4*)&Bs[r][cv] = *(const float4*)(G + (k0 + r) * DM + n0 + cv);
            }
        }
        __syncthreads();
#pragma unroll
        for (int k = 0; k < 32; ++k) {
            float4 a4 = *(const float4*)&As[k][tm];
            float4 b4 = *(const float4*)&Bs[k][tn];
            float af[4] = {a4.x, a4.y, a4.z, a4.w};
            float bf[4] = {b4.x, b4.y, b4.z, b4.w};
#pragma unroll
            for (int i = 0; i < 4; i++)
#pragma unroll
                for (int j = 0; j < 4; j++) acc[i][j] = fmaf(af[i], bf[j], acc[i][j]);
        }
    }
    float4 c4 = *(const float4*)(csum + n0 + tn);
#pragma unroll
    for (int i = 0; i < 4; i++) {
        int base = (m0 + tm + i) * DM + n0 + tn;
        float4 y4 = *(const float4*)(Yb + base);
        float4 o = {acc[i][0] * 0.2f - y4.x - THRC * c4.x,
                    acc[i][1] * 0.2f - y4.y - THRC * c4.y,
                    acc[i][2] * 0.2f - y4.z - THRC * c4.z,
                    acc[i][3] * 0.2f - y4.w - THRC * c4.w};
        *(float4*)(aD + base) = o;
    }
}

// fill s-planes with the pair of (-thr): s0 = P0 - thr = -thr  (P0 = 0)
__global__ void kinit_s(_Float16* __restrict__ SHp, _Float16* __restrict__ SLp) {
    size_t i = ((size_t)blockIdx.x * 256 + threadIdx.x) * 8;
    _Float16 h = (_Float16)(-THRC);
    _Float16 l = (_Float16)((-THRC - (float)h) * 64.f);
    f16x8 hv, lv;
#pragma unroll
    for (int e = 0; e < 8; e++) { hv[e] = h; lv[e] = l; }
    *(f16x8*)(SHp + i) = hv;
    *(f16x8*)(SLp + i) = lv;
}

// ---------------- loop kernels: pure fragment-streaming MFMA (no LDS, no barrier) ----

// GEMM1 partial: Qp[ks] = op(s) @ Dp over this ks's K-chunk of CP.
// MODE 0 (loop): op = |s| (exact pair sign-fold; -thr folded into kred via aD').
// MODE 1 (final): op = relu(s) = z.
// XCD map: raw%8 selects a ks-pair -> each XCD holds both A- and B-sharers in L2.
template <int MODE>
__global__ __launch_bounds__(256, 2) void kg1f(const _Float16* __restrict__ SHp,
                                               const _Float16* __restrict__ SLp,
                                               const _Float16* __restrict__ DHs,
                                               const _Float16* __restrict__ DLs,
                                               float* __restrict__ Qp) {
    const int raw = blockIdx.x;
    const int xcd = raw & 7;
    const int r   = raw >> 3;            // 0..63
    const int ks  = xcd * 2 + (r & 1);   // 0..15
    const int q   = r >> 1;              // 0..31
    const int mb  = q >> 2, nb = q & 3;
    const int n0 = nb * 128, m0 = mb * 128;
    const int tid = threadIdx.x;
    const int lane = tid & 63;
    const int wvu = tid >> 6;
    const int wm = (wvu >> 1) * 64, wn = (wvu & 1) * 64;
    f32x4 acc[4][4] = {};

    const int steps = CP / 32;                    // 316
    const int per = (steps + KSPL - 1) / KSPL;    // 20
    int s0 = ks * per;
    int s1 = s0 + per; if (s1 > steps) s1 = steps;

    const int mtb = (m0 + wm) >> 4;    // A fragment row-tile base (batch rows)
    const int ntb = (n0 + wn) >> 4;    // B fragment row-tile base (DM rows)
    const size_t lo = (size_t)lane * 8;

#pragma unroll 2
    for (int sp = s0; sp < s1; ++sp) {
        f16x8 ah[4], al[4], bh[4], bl[4];
#pragma unroll
        for (int i = 0; i < 4; i++) {
            size_t go = ((size_t)(mtb + i) * (CP / 32) + sp) * 512 + lo;
            ah[i] = *(const f16x8*)(SHp + go);
            al[i] = *(const f16x8*)(SLp + go);
        }
#pragma unroll
        for (int j = 0; j < 4; j++) {
            size_t go = ((size_t)(ntb + j) * (CP / 32) + sp) * 512 + lo;
            bh[j] = *(const f16x8*)(DHs + go);
            bl[j] = *(const f16x8*)(DLs + go);
        }
#pragma unroll
        for (int i = 0; i < 4; i++) {
            if (MODE == 0) absfold(ah[i], al[i]);
            else           relufold(ah[i], al[i]);
        }
        f16x8 as_[4], bs_[4];
#pragma unroll
        for (int i = 0; i < 4; i++) as_[i] = scl6(ah[i]);
#pragma unroll
        for (int j = 0; j < 4; j++) bs_[j] = scl6(bh[j]);
#pragma unroll
        for (int i = 0; i < 4; i++)
#pragma unroll
            for (int j = 0; j < 4; j++) {
                acc[i][j] = __builtin_amdgcn_mfma_f32_16x16x32_f16(ah[i],  bh[j], acc[i][j], 0, 0, 0);
                acc[i][j] = __builtin_amdgcn_mfma_f32_16x16x32_f16(as_[i], bl[j], acc[i][j], 0, 0, 0);
                acc[i][j] = __builtin_amdgcn_mfma_f32_16x16x32_f16(al[i],  bs_[j], acc[i][j], 0, 0, 0);
            }
    }
    float* outp = Qp + (size_t)ks * (BDIM * DM);
    const int r0 = (lane >> 4) * 4, c0l = lane & 15;
#pragma unroll
    for (int i = 0; i < 4; i++)
#pragma unroll
        for (int v = 0; v < 4; v++) {
            int row = m0 + wm + i * 16 + r0 + v;
#pragma unroll
            for (int j = 0; j < 4; j++)
                outp[(size_t)row * DM + n0 + wn + j * 16 + c0l] = acc[i][j][v];
        }
}

// Qf reduce: ADD=1 (loop): Qf = aD' + sum Qp -> write Qf h/l FRAGMENT PLANES.
//            ADD=0 (final): Qf = sum Qp -> write fp32 row-major to out32.
template <int ADD>
__global__ void kredf(const float* __restrict__ Qp, const float* __restrict__ aD,
                      float* __restrict__ out32, _Float16* __restrict__ QH,
                      _Float16* __restrict__ QL) {
    size_t b = ((size_t)blockIdx.x * 256 + threadIdx.x) * 4;
    float4 s = {0.f, 0.f, 0.f, 0.f};
    if (ADD) s = *(const float4*)(aD + b);
#pragma unroll
    for (int qq = 0; qq < KSPL; qq++) {
        float4 t = *(const float4*)(Qp + (size_t)qq * (BDIM * DM) + b);
        s.x += t.x; s.y += t.y; s.z += t.z; s.w += t.w;
    }
    if (ADD) {
        int row = (int)(b >> 9), col = (int)(b & 511);
        size_t t0 = ((size_t)(row >> 4) * 16 + (size_t)(col >> 5)) * 512
                  + (size_t)((((col >> 3) & 3) * 16 + (row & 15)) * 8 + (col & 7));
        float sv[4] = {s.x, s.y, s.z, s.w};
        f16x4 h4, l4;
#pragma unroll
        for (int e = 0; e < 4; e++) {
            _Float16 h = (_Float16)sv[e];
            h4[e] = h;
            l4[e] = (_Float16)((sv[e] - (float)h) * 64.f);
        }
        *(f16x4*)(QH + t0) = h4;
        *(f16x4*)(QL + t0) = l4;
    } else {
        *(float4*)(out32 + b) = s;
    }
}

// GEMM2: acc = Qf @ E^T (out [1024][CP], K=512), fused ADMM epilogue on s-planes:
//   s_old -> z = relu(s_old); P_new = a + z - acc; s_new = P_new - thr (pair stores).
// A from Qf planes, B from E planes: pure fragment streaming, no LDS/barrier.
// XCD map: raw%8 selects the nb-group so all 8 mb-sharers of a B-panel co-reside.
__global__ __launch_bounds__(256, 2) void kg2f(const _Float16* __restrict__ QH,
                                               const _Float16* __restrict__ QL,
                                               const _Float16* __restrict__ EHs,
                                               const _Float16* __restrict__ ELs,
                                               const _Float16* __restrict__ AH,
                                               _Float16* __restrict__ SHp,
                                               _Float16* __restrict__ SLp) {
    const int raw = blockIdx.x;
    const int g = raw & 7;
    const int q = raw >> 3;              // 0..79
    const int mb = q & 7, jj = q >> 3;   // jj 0..9
    const int nb = g * 10 + jj;
    if (nb >= 79) return;
    const int n0 = nb * 128, m0 = mb * 128;
    const int tid = threadIdx.x;
    const int lane = tid & 63;
    const int wvu = tid >> 6;
    const int wm = (wvu >> 1) * 64, wn = (wvu & 1) * 64;
    const int mtb = (m0 + wm) >> 4;
    const int ntb = (n0 + wn) >> 4;
    const size_t lo = (size_t)lane * 8;
    f32x4 acc[4][4] = {};

#pragma unroll 2
    for (int kk = 0; kk < DM / 32; ++kk) {
        f16x8 ah[4], al[4], bh[4], bl[4];
#pragma unroll
        for (int i = 0; i < 4; i++) {
            size_t go = ((size_t)(mtb + i) * (DM / 32) + kk) * 512 + lo;
            ah[i] = *(const f16x8*)(QH + go);
            al[i] = *(const f16x8*)(QL + go);
        }
#pragma unroll
        for (int j = 0; j < 4; j++) {
            size_t go = ((size_t)(ntb + j) * (DM / 32) + kk) * 512 + lo;
            bh[j] = *(const f16x8*)(EHs + go);
            bl[j] = *(const f16x8*)(ELs + go);
        }
        f16x8 as_[4], bs_[4];
#pragma unroll
        for (int i = 0; i < 4; i++) as_[i] = scl6(ah[i]);
#pragma unroll
        for (int j = 0; j < 4; j++) bs_[j] = scl6(bh[j]);
#pragma unroll
        for (int i = 0; i < 4; i++)
#pragma unroll
            for (int j = 0; j < 4; j++) {
                acc[i][j] = __builtin_amdgcn_mfma_f32_16x16x32_f16(ah[i],  bh[j], acc[i][j], 0, 0, 0);
                acc[i][j] = __builtin_amdgcn_mfma_f32_16x16x32_f16(as_[i], bl[j], acc[i][j], 0, 0, 0);
                acc[i][j] = __builtin_amdgcn_mfma_f32_16x16x32_f16(al[i],  bs_[j], acc[i][j], 0, 0, 0);
            }
    }
    const int r0 = (lane >> 4) * 4, c0l = lane & 15;
#pragma unroll
    for (int i = 0; i < 4; i++)
#pragma unroll
        for (int v = 0; v < 4; v++) {
            int row = m0 + wm + i * 16 + r0 + v;
#pragma unroll
            for (int j = 0; j < 4; j++) {
                int col = n0 + wn + j * 16 + c0l;
                size_t idx = (size_t)row * CP + col;
                size_t ps = psidx(row, col);
                float a = (float)AH[idx] * 0.015625f;
                float sold = (float)SHp[ps] + (float)SLp[ps] * 0.015625f;
                float z = fmaxf(sold, 0.f);
                float pn = a + z - acc[i][j][v];
                float sn = pn - THRC;
                _Float16 h = (_Float16)sn;
                SHp[ps] = h;
                SLp[ps] = (_Float16)((sn - (float)h) * 64.f);
            }
        }
}

// final: recon = normalize(normalize(Qf) + mean)
__global__ __launch_bounds__(256) void kfinal(const float* __restrict__ Qf,
                                              const float* __restrict__ mean,
                                              float* __restrict__ out) {
    int row = blockIdx.x, t = threadIdx.x;
    int off = row * DM + t * 2;
    float2 qv = *(const float2*)(Qf + off);
    float rx = qv.x, ry = qv.y;
    float ss = blk_sum256(rx * rx + ry * ry);
    float inv = 1.0f / fmaxf(sqrtf(ss), 1e-12f);
    rx *= inv; ry *= inv;
    float2 mm = *(const float2*)(mean + t * 2);
    rx += mm.x; ry += mm.y;
    float ss2 = blk_sum256(rx * rx + ry * ry);
    float inv2 = 1.0f / fmaxf(sqrtf(ss2), 1e-12f);
    float2 o = {rx * inv2, ry * inv2};
    *(float2*)(out + off) = o;
}

extern "C" void kernel_launch(void* const* d_in, const int* in_sizes, int n_in,
                              void* d_out, int out_size, void* d_ws, size_t ws_size,
                              hipStream_t stream) {
    const float* image = (const float*)d_in[0];
    const float* text  = (const float*)d_in[1];
    const float* mean  = (const float*)d_in[2];
    const float* D     = (const float*)d_in[3];
    float* out = (float*)d_out;
    float* ws = (float*)d_ws;

    // ---- workspace layout (float offsets); total 35,324,480 floats = 141.3 MB ----
    // (below the 145.8 MB the previous kernel used -> safely within proven ws_size)
    const size_t PLH = (size_t)DM * CP;                 // halfs per D/E plane
    float* aD   = ws;                                   // [1024][512] (also final Qf32)
    _Float16* QH = (_Float16*)(ws + 524288);            // Qf h-plane (frag-swizzled)
    _Float16* QL = QH + (size_t)BDIM * DM;              // Qf l-plane
    _Float16* DHs = (_Float16*)(ws + 1048576);          // D planes [DM][CP]
    _Float16* DLs = DHs + PLH;
    _Float16* EHs = DLs + PLH;                          // E planes [CP][DM]
    _Float16* ELs = EHs + PLH;
    _Float16* AH  = ELs + PLH;                          // a*64 fp16 [1024][CP] row-major
    _Float16* SH  = AH + (size_t)BDIM * CP;             // s h-plane (frag-swizzled [1024][CP])
    _Float16* SL  = SH + (size_t)BDIM * CP;             // s l-plane
    float* Qp   = (float*)(SL + (size_t)BDIM * CP);     // KSPL x [1024][512] partials
    float* csum = Qp + (size_t)KSPL * BDIM * DM;        // 512
    float* gmax = csum + 512;                           // 64
    // setup-only aliases (dead before kinit_s fills the s-planes):
    float* Dt32 = (float*)SH;                           // [512][CP] fp32
    float* G    = Dt32 + (size_t)DM * CP;
    float* Xa   = G + 262144;
    float* Xb   = Xa + 262144;
    float* Tns  = Xb + 262144;
    float* Y    = Tns + 262144;
    float* Et32 = (float*)AH;                           // [512][CP] fp32 (pre-AH)

    // --- setup ---
    knorm_rows<<<BDIM, 256, 0, stream>>>(text, out + (size_t)BDIM * DM);
    kprep_Y<<<BDIM, 256, 0, stream>>>(image, mean, Y);
    ktrs<<<dim3(CP / 64, DM / 64), 256, 0, stream>>>(D, Dt32, DHs, DLs, CREAL, DM, CP);
    kcsum<<<DM, 64, 0, stream>>>(Dt32, csum);
    kG<<<dim3(8, 8), 256, 0, stream>>>(Dt32, G);
    (void)hipMemsetAsync(gmax, 0, 4, stream);
    krow_abssum<<<DM, 64, 0, stream>>>(G, gmax);
    kinit_X0<<<DM * DM / 256, 256, 0, stream>>>(gmax, Xa);
    float* xc = Xa;
    float* xn = Xb;
    for (int it = 0; it < NSIT; ++it) {
        kgemm_ns_T<<<dim3(8, 8), 256, 0, stream>>>(G, xc, Tns);
        kgemm_ns_X<<<dim3(8, 8), 256, 0, stream>>>(xc, Tns, xn);
        float* tmp = xc; xc = xn; xn = tmp;
    }
    float* Ginv = xc;
    kgemm_nn64<0><<<dim3(CP / 64, DM / 64), 256, 0, stream>>>(Ginv, Dt32, Et32, nullptr);
    ktrs<<<dim3(DM / 64, CP / 64), 256, 0, stream>>>(Et32, nullptr, EHs, ELs, DM, CP, DM);
    kgemm_nn64<1><<<dim3(CP / 64, BDIM / 64), 256, 0, stream>>>(Y, Dt32, nullptr, AH);
    kgemm_aD<<<dim3(DM / 64, BDIM / 64), 256, 0, stream>>>(Y, G, csum, aD);
    // s0 = -thr everywhere (P0 = 0); clobbers all setup-only aliases (now dead)
    kinit_s<<<(int)((size_t)BDIM * CP / 8 / 256), 256, 0, stream>>>(SH, SL);

    // --- ADMM main loop: 3 barrier-free streaming kernels per iteration ---
    for (int it = 0; it < NIT; ++it) {
        kg1f<0><<<512, 256, 0, stream>>>(SH, SL, DHs, DLs, Qp);
        kredf<1><<<BDIM * DM / 1024, 256, 0, stream>>>(Qp, aD, nullptr, QH, QL);
        kg2f<<<640, 256, 0, stream>>>(QH, QL, EHs, ELs, AH, SH, SL);
    }

    // --- finalize: recon = normalize(normalize(z @ Dp) + mean), z = relu(s) ---
    kg1f<1><<<512, 256, 0, stream>>>(SH, SL, DHs, DLs, Qp);
    kredf<0><<<BDIM * DM / 1024, 256, 0, stream>>>(Qp, nullptr, aD, nullptr, nullptr);
    kfinal<<<BDIM, 256, 0, stream>>>(aD, mean, out);
}

// Round 2
// 12924.655 us; speedup vs baseline: 1.1021x; 1.1021x over previous
//
#include <hip/hip_runtime.h>
#include <cstddef>
#include <cstdint>

// Problem constants
#define BDIM  1024        // batch rows
#define DM    512         // embedding dim
#define CREAL 10000       // dictionary atoms
#define CP    10112       // padded atoms = 79*128 = 316*32
#define KSPL  16          // split-K chunks for GEMM1
#define RHOC  5.0f
#define THRC  (0.01f/5.0f)
#define NIT   100
#define NSIT  12

typedef float f32x4 __attribute__((ext_vector_type(4)));
typedef _Float16 f16x8 __attribute__((ext_vector_type(8)));
typedef _Float16 f16x4 __attribute__((ext_vector_type(4)));
typedef unsigned int u32x4 __attribute__((ext_vector_type(4)));

// ---------------- helpers ----------------

// Pair scheme: x ~ h + l/64, h=fp16(x), l=fp16((x-h)*64). GEMM uses 3 terms:
// h*h + (h*2^-6)*l + l*(h*2^-6)  (l*l dropped, ~2^-24 rel).
__device__ __forceinline__ f16x8 scl6(f16x8 v) {
    f16x8 r;
#pragma unroll
    for (int i = 0; i < 8; i++) r[i] = v[i] * (_Float16)0.015625f;  // exact exponent shift
    return r;
}

// |s| on an (h,l) pair is EXACT: flip both signs where h is negative.
__device__ __forceinline__ void absfold(f16x8& h8, f16x8& l8) {
    u32x4 h = __builtin_bit_cast(u32x4, h8);
    u32x4 l = __builtin_bit_cast(u32x4, l8);
    u32x4 m = h & 0x80008000u;
    h8 = __builtin_bit_cast(f16x8, h ^ m);
    l8 = __builtin_bit_cast(f16x8, l ^ m);
}

// relu(s) on an (h,l) pair: zero both where h<=0 (edge err ~2^-24, negligible).
__device__ __forceinline__ void relufold(f16x8& h8, f16x8& l8) {
#pragma unroll
    for (int e = 0; e < 8; e++) {
        bool p = h8[e] > (_Float16)0;
        if (!p) { h8[e] = (_Float16)0; l8[e] = (_Float16)0; }
    }
}

// fragment-swizzled plane index for an A-operand matrix [rows][C]:
//   idx = ((row>>4)*(C>>5) + (col>>5))*512 + (((col>>3)&3)*16 + (row&15))*8 + (col&7)
// so a wave's fragment load for (rowtile, coltile32) is base + lane*8.
__device__ __forceinline__ size_t psidx(int row, int col) {   // C = CP (s-planes)
    return ((size_t)(row >> 4) * (CP >> 5) + (size_t)(col >> 5)) * 512
         + (size_t)((((col >> 3) & 3) * 16 + (row & 15)) * 8 + (col & 7));
}

__device__ __forceinline__ float blk_sum256(float v) {
    __shared__ float sb[4];
#pragma unroll
    for (int o = 32; o; o >>= 1) v += __shfl_down(v, o, 64);
    int lane = threadIdx.x & 63, w = threadIdx.x >> 6;
    __syncthreads();
    if (lane == 0) sb[w] = v;
    __syncthreads();
    return sb[0] + sb[1] + sb[2] + sb[3];
}

// txt = normalize(text) per row
__global__ __launch_bounds__(256) void knorm_rows(const float* __restrict__ X,
                                                  float* __restrict__ out) {
    int row = blockIdx.x, t = threadIdx.x;
    int off = row * DM + t * 2;
    float2 v = *(const float2*)(X + off);
    float ss = blk_sum256(v.x * v.x + v.y * v.y);
    float inv = 1.0f / fmaxf(sqrtf(ss), 1e-12f);
    float2 o = {v.x * inv, v.y * inv};
    *(float2*)(out + off) = o;
}

// Y = normalize(normalize(image) - mean) per row
__global__ __launch_bounds__(256) void kprep_Y(const float* __restrict__ img,
                                               const float* __restrict__ mean,
                                               float* __restrict__ Y) {
    int row = blockIdx.x, t = threadIdx.x;
    int off = row * DM + t * 2;
    float2 v = *(const float2*)(img + off);
    float ss = blk_sum256(v.x * v.x + v.y * v.y);
    float inv = 1.0f / fmaxf(sqrtf(ss), 1e-12f);
    float2 mm = *(const float2*)(mean + t * 2);
    float tx = v.x * inv - mm.x, ty = v.y * inv - mm.y;
    float ss2 = blk_sum256(tx * tx + ty * ty);
    float inv2 = 1.0f / fmaxf(sqrtf(ss2), 1e-12f);
    float2 o = {tx * inv2, ty * inv2};
    *(float2*)(Y + off) = o;
}

// transpose (+zero-pad rows>=Rvalid), split to fp16 h/l pair (l stored *64) and write
// the fp16 planes in MFMA FRAGMENT-SWIZZLED order (see psidx formula).
// optional fp32 out = reconstructed pair, ROW-MAJOR.
__global__ __launch_bounds__(256) void ktrs(const float* __restrict__ in,
                                            float* __restrict__ out32,
                                            _Float16* __restrict__ oH,
                                            _Float16* __restrict__ oL,
                                            int Rvalid, int Cin, int Rout) {
    __shared__ float tile[64][65];
    int r0 = blockIdx.x * 64;   // rows of in  (cols of out)
    int c0 = blockIdx.y * 64;   // cols of in  (rows of out)
    int t = threadIdx.x;
    int ri = r0 + (t >> 2);
    int cc = (t & 3) * 16;
#pragma unroll
    for (int q = 0; q < 4; ++q) {
        float4 v = {0.f, 0.f, 0.f, 0.f};
        if (ri < Rvalid) v = *(const float4*)(in + (size_t)ri * Cin + c0 + cc + q * 4);
        *(float4*)&tile[t >> 2][cc + q * 4] = v;
    }
    __syncthreads();
    int oc = c0 + (t >> 2);            // out row
    int orr = r0 + (t & 3) * 16;       // out col base (multiple of 16)
    _Float16 hv[16], lv[16];
#pragma unroll
    for (int q = 0; q < 16; ++q) {
        float v = tile[(t & 3) * 16 + q][t >> 2];
        _Float16 h = (_Float16)v;
        _Float16 l = (_Float16)((v - (float)h) * 64.f);
        hv[q] = h; lv[q] = l;
        if (out32) out32[(size_t)oc * Rout + orr + q] = (float)h + (float)l * 0.015625f;
    }
    int rt = oc >> 4, rin = oc & 15;
    int kt = orr >> 5;
    int kq0 = (orr >> 3) & 3;          // 0 or 2
    size_t base = ((size_t)rt * (Rout >> 5) + kt) * 512;
    *(f16x8*)(oH + base + (size_t)(kq0 * 16 + rin) * 8)       = *(f16x8*)&hv[0];
    *(f16x8*)(oH + base + (size_t)((kq0 + 1) * 16 + rin) * 8) = *(f16x8*)&hv[8];
    *(f16x8*)(oL + base + (size_t)(kq0 * 16 + rin) * 8)       = *(f16x8*)&lv[0];
    *(f16x8*)(oL + base + (size_t)((kq0 + 1) * 16 + rin) * 8) = *(f16x8*)&lv[8];
}

// csum[n] = sum_k Dt[n][k]  (deterministic per-row wave reduce)
__global__ void kcsum(const float* __restrict__ Dt, float* __restrict__ csum) {
    int n = blockIdx.x, t = threadIdx.x;   // 64 threads = 1 wave
    float s = 0.f;
    for (int k = t; k < CP; k += 64) s += Dt[(size_t)n * CP + k];
#pragma unroll
    for (int o = 32; o; o >>= 1) s += __shfl_down(s, o, 64);
    if (t == 0) csum[n] = s;
}

// G = Dt*Dt^T + rho I  (Dt [512][CP] fp32; 64x64 tiles, K=CP)
__global__ __launch_bounds__(256) void kG(const float* __restrict__ Dt,
                                          float* __restrict__ G) {
    __shared__ float As[32][68];
    __shared__ float Bs[32][68];
    int tid = threadIdx.x;
    int j0 = blockIdx.x * 64, i0 = blockIdx.y * 64;
    int tn = (tid & 15) * 4, tm = (tid >> 4) * 4;
    float acc[4][4];
#pragma unroll
    for (int i = 0; i < 4; i++)
#pragma unroll
        for (int j = 0; j < 4; j++) acc[i][j] = 0.f;
    for (int k0 = 0; k0 < CP; k0 += 32) {
        __syncthreads();
#pragma unroll
        for (int p = 0; p < 2; ++p) {
            int idx = tid + p * 256;
            int row = idx >> 3, kv = (idx & 7) << 2;
            float4 va = *(const float4*)(Dt + (size_t)(i0 + row) * CP + k0 + kv);
            As[kv + 0][row] = va.x; As[kv + 1][row] = va.y;
            As[kv + 2][row] = va.z; As[kv + 3][row] = va.w;
            float4 vb = *(const float4*)(Dt + (size_t)(j0 + row) * CP + k0 + kv);
            Bs[kv + 0][row] = vb.x; Bs[kv + 1][row] = vb.y;
            Bs[kv + 2][row] = vb.z; Bs[kv + 3][row] = vb.w;
        }
        __syncthreads();
#pragma unroll
        for (int k = 0; k < 32; ++k) {
            float4 a4 = *(const float4*)&As[k][tm];
            float4 b4 = *(const float4*)&Bs[k][tn];
            float af[4] = {a4.x, a4.y, a4.z, a4.w};
            float bf[4] = {b4.x, b4.y, b4.z, b4.w};
#pragma unroll
            for (int i = 0; i < 4; i++)
#pragma unroll
                for (int j = 0; j < 4; j++) acc[i][j] = fmaf(af[i], bf[j], acc[i][j]);
        }
    }
#pragma unroll
    for (int i = 0; i < 4; i++)
#pragma unroll
        for (int j = 0; j < 4; j++) {
            int gi = i0 + tm + i, gj = j0 + tn + j;
            G[gi * DM + gj] = acc[i][j] + ((gi == gj) ? RHOC : 0.f);
        }
}

__global__ void krow_abssum(const float* __restrict__ G, float* __restrict__ gmax) {
    int row = blockIdx.x, t = threadIdx.x;   // 64 threads = 1 wave
    float s = 0.f;
    for (int j = t; j < DM; j += 64) s += fabsf(G[row * DM + j]);
#pragma unroll
    for (int o = 32; o; o >>= 1) s += __shfl_down(s, o, 64);
    if (t == 0) atomicMax((int*)gmax, __float_as_int(s));
}

__global__ void kinit_X0(const float* __restrict__ gmax, float* __restrict__ X) {
    int idx = blockIdx.x * 256 + threadIdx.x;
    int i = idx >> 9, j = idx & 511;
    X[idx] = (i == j) ? (1.0f / gmax[0]) : 0.0f;
}

// T = G @ X (512^3 NN, 64x64 tiles)
__global__ __launch_bounds__(256) void kgemm_ns_T(const float* __restrict__ G,
                                                  const float* __restrict__ X,
                                                  float* __restrict__ T) {
    __shared__ float As[32][68];
    __shared__ float Bs[32][68];
    int tid = threadIdx.x;
    int n0 = blockIdx.x * 64, m0 = blockIdx.y * 64;
    int tn = (tid & 15) * 4, tm = (tid >> 4) * 4;
    float acc[4][4];
#pragma unroll
    for (int i = 0; i < 4; i++)
#pragma unroll
        for (int j = 0; j < 4; j++) acc[i][j] = 0.f;
    for (int k0 = 0; k0 < DM; k0 += 32) {
        __syncthreads();
#pragma unroll
        for (int p = 0; p < 2; ++p) {
            int idx = tid + p * 256;
            {
                int row = idx >> 3, kv = (idx & 7) << 2;
                float4 v = *(const float4*)(G + (m0 + row) * DM + k0 + kv);
                As[kv + 0][row] = v.x; As[kv + 1][row] = v.y;
                As[kv + 2][row] = v.z; As[kv + 3][row] = v.w;
            }
            {
                int r = idx >> 4, cv = (idx & 15) << 2;
                *(float4*)&Bs[r][cv] = *(const float4*)(X + (k0 + r) * DM + n0 + cv);
            }
        }
        __syncthreads();
#pragma unroll
        for (int k = 0; k < 32; ++k) {
            float4 a4 = *(const float4*)&As[k][tm];
            float4 b4 = *(const float4*)&Bs[k][tn];
            float af[4] = {a4.x, a4.y, a4.z, a4.w};
            float bf[4] = {b4.x, b4.y, b4.z, b4.w};
#pragma unroll
            for (int i = 0; i < 4; i++)
#pragma unroll
                for (int j = 0; j < 4; j++) acc[i][j] = fmaf(af[i], bf[j], acc[i][j]);
        }
    }
#pragma unroll
    for (int i = 0; i < 4; i++) {
        float4 o = {acc[i][0], acc[i][1], acc[i][2], acc[i][3]};
        *(float4*)(T + (m0 + tm + i) * DM + n0 + tn) = o;
    }
}

// Xn = 2*Xo - Xo @ T
__global__ __launch_bounds__(256) void kgemm_ns_X(const float* __restrict__ Xo,
                                                  const float* __restrict__ T,
                                                  float* __restrict__ Xn) {
    __shared__ float As[32][68];
    __shared__ float Bs[32][68];
    int tid = threadIdx.x;
    int n0 = blockIdx.x * 64, m0 = blockIdx.y * 64;
    int tn = (tid & 15) * 4, tm = (tid >> 4) * 4;
    float acc[4][4];
#pragma unroll
    for (int i = 0; i < 4; i++)
#pragma unroll
        for (int j = 0; j < 4; j++) acc[i][j] = 0.f;
    for (int k0 = 0; k0 < DM; k0 += 32) {
        __syncthreads();
#pragma unroll
        for (int p = 0; p < 2; ++p) {
            int idx = tid + p * 256;
            {
                int row = idx >> 3, kv = (idx & 7) << 2;
                float4 v = *(const float4*)(Xo + (m0 + row) * DM + k0 + kv);
                As[kv + 0][row] = v.x; As[kv + 1][row] = v.y;
                As[kv + 2][row] = v.z; As[kv + 3][row] = v.w;
            }
            {
                int r = idx >> 4, cv = (idx & 15) << 2;
                *(float4*)&Bs[r][cv] = *(const float4*)(T + (k0 + r) * DM + n0 + cv);
            }
        }
        __syncthreads();
#pragma unroll
        for (int k = 0; k < 32; ++k) {
            float4 a4 = *(const float4*)&As[k][tm];
            float4 b4 = *(const float4*)&Bs[k][tn];
            float af[4] = {a4.x, a4.y, a4.z, a4.w};
            float bf[4] = {b4.x, b4.y, b4.z, b4.w};
#pragma unroll
            for (int i = 0; i < 4; i++)
#pragma unroll
                for (int j = 0; j < 4; j++) acc[i][j] = fmaf(af[i], bf[j], acc[i][j]);
        }
    }
#pragma unroll
    for (int i = 0; i < 4; i++) {
        int base = (m0 + tm + i) * DM + n0 + tn;
        float4 xo = *(const float4*)(Xo + base);
        float4 o = {2.f * xo.x - acc[i][0], 2.f * xo.y - acc[i][1],
                    2.f * xo.z - acc[i][2], 2.f * xo.w - acc[i][3]};
        *(float4*)(Xn + base) = o;
    }
}

// NN fp32: out[M][CP] = A[M][512] @ B[512][CP]
// MODE 0: store fp32. MODE 1: store a = acc*0.2 as fp16 scaled by 64.
template <int MODE>
__global__ __launch_bounds__(256) void kgemm_nn64(const float* __restrict__ A,
                                                  const float* __restrict__ B,
                                                  float* __restrict__ out32,
                                                  _Float16* __restrict__ oA) {
    __shared__ float As[32][68];
    __shared__ float Bs[32][68];
    int tid = threadIdx.x;
    int n0 = blockIdx.x * 64, m0 = blockIdx.y * 64;
    int tn = (tid & 15) * 4, tm = (tid >> 4) * 4;
    float acc[4][4];
#pragma unroll
    for (int i = 0; i < 4; i++)
#pragma unroll
        for (int j = 0; j < 4; j++) acc[i][j] = 0.f;
    for (int k0 = 0; k0 < DM; k0 += 32) {
        __syncthreads();
#pragma unroll
        for (int p = 0; p < 2; ++p) {
            int idx = tid + p * 256;
            {
                int row = idx >> 3, kv = (idx & 7) << 2;
                float4 v = *(const float4*)(A + (size_t)(m0 + row) * DM + k0 + kv);
                As[kv + 0][row] = v.x; As[kv + 1][row] = v.y;
                As[kv + 2][row] = v.z; As[kv + 3][row] = v.w;
            }
            {
                int r = idx >> 4, cv = (idx & 15) << 2;
                *(float4*)&Bs[r][cv] = *(const float4*)(B + (size_t)(k0 + r) * CP + n0 + cv);
            }
        }
        __syncthreads();
#pragma unroll
        for (int k = 0; k < 32; ++k) {
            float4 a4 = *(const float4*)&As[k][tm];
            float4 b4 = *(const float4*)&Bs[k][tn];
            float af[4] = {a4.x, a4.y, a4.z, a4.w};
            float bf[4] = {b4.x, b4.y, b4.z, b4.w};
#pragma unroll
            for (int i = 0; i < 4; i++)
#pragma unroll
                for (int j = 0; j < 4; j++) acc[i][j] = fmaf(af[i], bf[j], acc[i][j]);
        }
    }
#pragma unroll
    for (int i = 0; i < 4; i++)
#pragma unroll
        for (int j = 0; j < 4; j++) {
            size_t idx = (size_t)(m0 + tm + i) * CP + n0 + tn + j;
            if (MODE == 0) out32[idx] = acc[i][j];
            else           oA[idx] = (_Float16)(acc[i][j] * 0.2f * 64.f);
        }
}

// aD = Y@G/rho - Y - thr*csum   (out [1024][512]; 64x64 tiles, K=512)
// the -thr*csum term folds GEMM1's constant correction: v = |s| - thr.
__global__ __launch_bounds__(256) void kgemm_aD(const float* __restrict__ Yb,
                                                const float* __restrict__ G,
                                                const float* __restrict__ csum,
                                                float* __restrict__ aD) {
    __shared__ float As[32][68];
    __shared__ float Bs[32][68];
    int tid = threadIdx.x;
    int n0 = blockIdx.x * 64, m0 = blockIdx.y * 64;
    int tn = (tid & 15) * 4, tm = (tid >> 4) * 4;
    float acc[4][4];
#pragma unroll
    for (int i = 0; i < 4; i++)
#pragma unroll
        for (int j = 0; j < 4; j++) acc[i][j] = 0.f;
    for (int k0 = 0; k0 < DM; k0 += 32) {
        __syncthreads();
#pragma unroll
        for (int p = 0; p < 2; ++p) {
            int idx = tid + p * 256;
            {
                int row = idx >> 3, kv = (idx & 7) << 2;
                float4 v = *(const float4*)(Yb + (size_t)(m0 + row) * DM + k0 + kv);
                As[kv + 0][row] = v.x; As[kv + 1][row] = v.y;
                As[kv + 2][row] = v.z; As[kv + 3][row] = v.w;
            }
            {
                int r = idx >> 4, cv = (idx & 15) << 2;
                *(float4*)&Bs[r][cv] = *(const float4*)(G + (k0 + r) * DM + n0 + cv);
            }
        }
        __syncthreads();
#pragma unroll
        for (int k = 0; k < 32; ++k) {
            float4 a4 = *(const float4*)&As[k][tm];
            float4 b4 = *(const float4*)&Bs[k][tn];
            float af[4] = {a4.x, a4.y, a4.z, a4.w};
            float bf[4] = {b4.x, b4.y, b4.z, b4.w};
#pragma unroll
            for (int i = 0; i < 4; i++)
#pragma unroll
                for (int j = 0; j < 4; j++) acc[i][j] = fmaf(af[i], bf[j], acc[i][j]);
        }
    }
    float4 c4 = *(const float4*)(csum + n0 + tn);
#pragma unroll
    for (int i = 0; i < 4; i++) {
        int base = (m0 + tm + i) * DM + n0 + tn;
        float4 y4 = *(const float4*)(Yb + base);
        float4 o = {acc[i][0] * 0.2f - y4.x - THRC * c4.x,
                    acc[i][1] * 0.2f - y4.y - THRC * c4.y,
                    acc[i][2] * 0.2f - y4.z - THRC * c4.z,
                    acc[i][3] * 0.2f - y4.w - THRC * c4.w};
        *(float4*)(aD + base) = o;
    }
}

// fill s-planes with the pair of (-thr): s0 = P0 - thr = -thr  (P0 = 0)
__global__ void kinit_s(_Float16* __restrict__ SHp, _Float16* __restrict__ SLp) {
    size_t i = ((size_t)blockIdx.x * 256 + threadIdx.x) * 8;
    _Float16 h = (_Float16)(-THRC);
    _Float16 l = (_Float16)((-THRC - (float)h) * 64.f);
    f16x8 hv, lv;
#pragma unroll
    for (int e = 0; e < 8; e++) { hv[e] = h; lv[e] = l; }
    *(f16x8*)(SHp + i) = hv;
    *(f16x8*)(SLp + i) = lv;
}

// ---------------- loop kernels: fragment streaming + explicit 2-deep prefetch ------

// One k-step's worth of fragments (A h/l + B h/l). Statically indexed only.
struct Frag {
    f16x8 ah[4], al[4], bh[4], bl[4];
};

// issue the 16 fragment loads for step sp into f (no waits here; compiler inserts
// counted vmcnt before first USE, so these overlap the other buffer's MFMAs)
__device__ __forceinline__ void frag_load(Frag& f,
                                          const _Float16* __restrict__ AHp,
                                          const _Float16* __restrict__ ALp,
                                          const _Float16* __restrict__ BHp,
                                          const _Float16* __restrict__ BLp,
                                          int sp, int mtb, int ntb, int kt,
                                          size_t lo) {
#pragma unroll
    for (int i = 0; i < 4; i++) {
        size_t go = ((size_t)(mtb + i) * kt + sp) * 512 + lo;
        f.ah[i] = *(const f16x8*)(AHp + go);
        f.al[i] = *(const f16x8*)(ALp + go);
    }
#pragma unroll
    for (int j = 0; j < 4; j++) {
        size_t go = ((size_t)(ntb + j) * kt + sp) * 512 + lo;
        f.bh[j] = *(const f16x8*)(BHp + go);
        f.bl[j] = *(const f16x8*)(BLp + go);
    }
}

// 48-MFMA compute cluster on one buffer. FOLD: 0=abs, 1=relu, 2=none.
template <int FOLD>
__device__ __forceinline__ void frag_compute(Frag& f, f32x4 (&acc)[4][4]) {
#pragma unroll
    for (int i = 0; i < 4; i++) {
        if (FOLD == 0) absfold(f.ah[i], f.al[i]);
        else if (FOLD == 1) relufold(f.ah[i], f.al[i]);
    }
    f16x8 as_[4], bs_[4];
#pragma unroll
    for (int i = 0; i < 4; i++) as_[i] = scl6(f.ah[i]);
#pragma unroll
    for (int j = 0; j < 4; j++) bs_[j] = scl6(f.bh[j]);
#pragma unroll
    for (int i = 0; i < 4; i++)
#pragma unroll
        for (int j = 0; j < 4; j++) {
            acc[i][j] = __builtin_amdgcn_mfma_f32_16x16x32_f16(f.ah[i],  f.bh[j], acc[i][j], 0, 0, 0);
            acc[i][j] = __builtin_amdgcn_mfma_f32_16x16x32_f16(as_[i],   f.bl[j], acc[i][j], 0, 0, 0);
            acc[i][j] = __builtin_amdgcn_mfma_f32_16x16x32_f16(f.al[i],  bs_[j],  acc[i][j], 0, 0, 0);
        }
}

// GEMM1 partial: Qp[ks] = op(s) @ Dp over this ks's K-chunk of CP.
// MODE 0 (loop): op = |s| (exact pair sign-fold; -thr folded into kred via aD').
// MODE 1 (final): op = relu(s) = z.
// XCD map: raw%8 selects a ks-pair -> each XCD holds both A- and B-sharers in L2.
// Step count per ks is 20 (or 16 for the last) -> always EVEN, so the 2-step
// software pipeline below has no tail.
template <int MODE>
__global__ __launch_bounds__(256, 2) void kg1f(const _Float16* __restrict__ SHp,
                                               const _Float16* __restrict__ SLp,
                                               const _Float16* __restrict__ DHs,
                                               const _Float16* __restrict__ DLs,
                                               float* __restrict__ Qp) {
    const int raw = blockIdx.x;
    const int xcd = raw & 7;
    const int r   = raw >> 3;            // 0..63
    const int ks  = xcd * 2 + (r & 1);   // 0..15
    const int q   = r >> 1;              // 0..31
    const int mb  = q >> 2, nb = q & 3;
    const int n0 = nb * 128, m0 = mb * 128;
    const int tid = threadIdx.x;
    const int lane = tid & 63;
    const int wvu = tid >> 6;
    const int wm = (wvu >> 1) * 64, wn = (wvu & 1) * 64;
    f32x4 acc[4][4] = {};

    const int steps = CP / 32;                    // 316
    const int per = (steps + KSPL - 1) / KSPL;    // 20
    int s0 = ks * per;
    int s1 = s0 + per; if (s1 > steps) s1 = steps;

    const int mtb = (m0 + wm) >> 4;    // A fragment row-tile base (batch rows)
    const int ntb = (n0 + wn) >> 4;    // B fragment row-tile base (DM rows)
    const size_t lo = (size_t)lane * 8;

    Frag fA, fB;
    frag_load(fA, SHp, SLp, DHs, DLs, s0, mtb, ntb, CP / 32, lo);
    for (int sp = s0; sp < s1; sp += 2) {
        frag_load(fB, SHp, SLp, DHs, DLs, sp + 1, mtb, ntb, CP / 32, lo);
        frag_compute<MODE>(fA, acc);
        if (sp + 2 < s1)
            frag_load(fA, SHp, SLp, DHs, DLs, sp + 2, mtb, ntb, CP / 32, lo);
        frag_compute<MODE>(fB, acc);
    }

    float* outp = Qp + (size_t)ks * (BDIM * DM);
    const int r0 = (lane >> 4) * 4, c0l = lane & 15;
#pragma unroll
    for (int i = 0; i < 4; i++)
#pragma unroll
        for (int v = 0; v < 4; v++) {
            int row = m0 + wm + i * 16 + r0 + v;
#pragma unroll
            for (int j = 0; j < 4; j++)
                outp[(size_t)row * DM + n0 + wn + j * 16 + c0l] = acc[i][j][v];
        }
}

// Qf reduce: ADD=1 (loop): Qf = aD' + sum Qp -> write Qf h/l FRAGMENT PLANES.
//            ADD=0 (final): Qf = sum Qp -> write fp32 row-major to out32.
template <int ADD>
__global__ void kredf(const float* __restrict__ Qp, const float* __restrict__ aD,
                      float* __restrict__ out32, _Float16* __restrict__ QH,
                      _Float16* __restrict__ QL) {
    size_t b = ((size_t)blockIdx.x * 256 + threadIdx.x) * 4;
    float4 s = {0.f, 0.f, 0.f, 0.f};
    if (ADD) s = *(const float4*)(aD + b);
#pragma unroll
    for (int qq = 0; qq < KSPL; qq++) {
        float4 t = *(const float4*)(Qp + (size_t)qq * (BDIM * DM) + b);
        s.x += t.x; s.y += t.y; s.z += t.z; s.w += t.w;
    }
    if (ADD) {
        int row = (int)(b >> 9), col = (int)(b & 511);
        size_t t0 = ((size_t)(row >> 4) * 16 + (size_t)(col >> 5)) * 512
                  + (size_t)((((col >> 3) & 3) * 16 + (row & 15)) * 8 + (col & 7));
        float sv[4] = {s.x, s.y, s.z, s.w};
        f16x4 h4, l4;
#pragma unroll
        for (int e = 0; e < 4; e++) {
            _Float16 h = (_Float16)sv[e];
            h4[e] = h;
            l4[e] = (_Float16)((sv[e] - (float)h) * 64.f);
        }
        *(f16x4*)(QH + t0) = h4;
        *(f16x4*)(QL + t0) = l4;
    } else {
        *(float4*)(out32 + b) = s;
    }
}

// GEMM2: acc = Qf @ E^T (out [1024][CP], K=512), fused ADMM epilogue on s-planes:
//   s_old -> z = relu(s_old); P_new = a + z - acc; s_new = P_new - thr (pair stores).
// A from Qf planes, B from E planes. 16 k-steps (even) -> clean 2-step pipeline.
// XCD map: raw%8 selects the nb-group so all 8 mb-sharers of a B-panel co-reside.
__global__ __launch_bounds__(256, 2) void kg2f(const _Float16* __restrict__ QH,
                                               const _Float16* __restrict__ QL,
                                               const _Float16* __restrict__ EHs,
                                               const _Float16* __restrict__ ELs,
                                               const _Float16* __restrict__ AH,
                                               _Float16* __restrict__ SHp,
                                               _Float16* __restrict__ SLp) {
    const int raw = blockIdx.x;
    const int g = raw & 7;
    const int q = raw >> 3;              // 0..79
    const int mb = q & 7, jj = q >> 3;   // jj 0..9
    const int nb = g * 10 + jj;
    if (nb >= 79) return;
    const int n0 = nb * 128, m0 = mb * 128;
    const int tid = threadIdx.x;
    const int lane = tid & 63;
    const int wvu = tid >> 6;
    const int wm = (wvu >> 1) * 64, wn = (wvu & 1) * 64;
    const int mtb = (m0 + wm) >> 4;
    const int ntb = (n0 + wn) >> 4;
    const size_t lo = (size_t)lane * 8;
    f32x4 acc[4][4] = {};

    Frag fA, fB;
    frag_load(fA, QH, QL, EHs, ELs, 0, mtb, ntb, DM / 32, lo);
    for (int kk = 0; kk < DM / 32; kk += 2) {
        frag_load(fB, QH, QL, EHs, ELs, kk + 1, mtb, ntb, DM / 32, lo);
        frag_compute<2>(fA, acc);
        if (kk + 2 < DM / 32)
            frag_load(fA, QH, QL, EHs, ELs, kk + 2, mtb, ntb, DM / 32, lo);
        frag_compute<2>(fB, acc);
    }

    const int r0 = (lane >> 4) * 4, c0l = lane & 15;
#pragma unroll
    for (int i = 0; i < 4; i++)
#pragma unroll
        for (int v = 0; v < 4; v++) {
            int row = m0 + wm + i * 16 + r0 + v;
#pragma unroll
            for (int j = 0; j < 4; j++) {
                int col = n0 + wn + j * 16 + c0l;
                size_t idx = (size_t)row * CP + col;
                size_t ps = psidx(row, col);
                float a = (float)AH[idx] * 0.015625f;
                float sold = (float)SHp[ps] + (float)SLp[ps] * 0.015625f;
                float z = fmaxf(sold, 0.f);
                float pn = a + z - acc[i][j][v];
                float sn = pn - THRC;
                _Float16 h = (_Float16)sn;
                SHp[ps] = h;
                SLp[ps] = (_Float16)((sn - (float)h) * 64.f);
            }
        }
}

// final: recon = normalize(normalize(Qf) + mean)
__global__ __launch_bounds__(256) void kfinal(const float* __restrict__ Qf,
                                              const float* __restrict__ mean,
                                              float* __restrict__ out) {
    int row = blockIdx.x, t = threadIdx.x;
    int off = row * DM + t * 2;
    float2 qv = *(const float2*)(Qf + off);
    float rx = qv.x, ry = qv.y;
    float ss = blk_sum256(rx * rx + ry * ry);
    float inv = 1.0f / fmaxf(sqrtf(ss), 1e-12f);
    rx *= inv; ry *= inv;
    float2 mm = *(const float2*)(mean + t * 2);
    rx += mm.x; ry += mm.y;
    float ss2 = blk_sum256(rx * rx + ry * ry);
    float inv2 = 1.0f / fmaxf(sqrtf(ss2), 1e-12f);
    float2 o = {rx * inv2, ry * inv2};
    *(float2*)(out + off) = o;
}

extern "C" void kernel_launch(void* const* d_in, const int* in_sizes, int n_in,
                              void* d_out, int out_size, void* d_ws, size_t ws_size,
                              hipStream_t stream) {
    const float* image = (const float*)d_in[0];
    const float* text  = (const float*)d_in[1];
    const float* mean  = (const float*)d_in[2];
    const float* D     = (const float*)d_in[3];
    float* out = (float*)d_out;
    float* ws = (float*)d_ws;

    // ---- workspace layout (float offsets); total 35,324,480 floats = 141.3 MB ----
    const size_t PLH = (size_t)DM * CP;                 // halfs per D/E plane
    float* aD   = ws;                                   // [1024][512] (also final Qf32)
    _Float16* QH = (_Float16*)(ws + 524288);            // Qf h-plane (frag-swizzled)
    _Float16* QL = QH + (size_t)BDIM * DM;              // Qf l-plane
    _Float16* DHs = (_Float16*)(ws + 1048576);          // D planes [DM][CP]
    _Float16* DLs = DHs + PLH;
    _Float16* EHs = DLs + PLH;                          // E planes [CP][DM]
    _Float16* ELs = EHs + PLH;
    _Float16* AH  = ELs + PLH;                          // a*64 fp16 [1024][CP] row-major
    _Float16* SH  = AH + (size_t)BDIM * CP;             // s h-plane (frag-swizzled [1024][CP])
    _Float16* SL  = SH + (size_t)BDIM * CP;             // s l-plane
    float* Qp   = (float*)(SL + (size_t)BDIM * CP);     // KSPL x [1024][512] partials
    float* csum = Qp + (size_t)KSPL * BDIM * DM;        // 512
    float* gmax = csum + 512;                           // 64
    // setup-only aliases (dead before kinit_s fills the s-planes):
    float* Dt32 = (float*)SH;                           // [512][CP] fp32
    float* G    = Dt32 + (size_t)DM * CP;
    float* Xa   = G + 262144;
    float* Xb   = Xa + 262144;
    float* Tns  = Xb + 262144;
    float* Y    = Tns + 262144;
    float* Et32 = (float*)AH;                           // [512][CP] fp32 (pre-AH)

    // --- setup ---
    knorm_rows<<<BDIM, 256, 0, stream>>>(text, out + (size_t)BDIM * DM);
    kprep_Y<<<BDIM, 256, 0, stream>>>(image, mean, Y);
    ktrs<<<dim3(CP / 64, DM / 64), 256, 0, stream>>>(D, Dt32, DHs, DLs, CREAL, DM, CP);
    kcsum<<<DM, 64, 0, stream>>>(Dt32, csum);
    kG<<<dim3(8, 8), 256, 0, stream>>>(Dt32, G);
    (void)hipMemsetAsync(gmax, 0, 4, stream);
    krow_abssum<<<DM, 64, 0, stream>>>(G, gmax);
    kinit_X0<<<DM * DM / 256, 256, 0, stream>>>(gmax, Xa);
    float* xc = Xa;
    float* xn = Xb;
    for (int it = 0; it < NSIT; ++it) {
        kgemm_ns_T<<<dim3(8, 8), 256, 0, stream>>>(G, xc, Tns);
        kgemm_ns_X<<<dim3(8, 8), 256, 0, stream>>>(xc, Tns, xn);
        float* tmp = xc; xc = xn; xn = tmp;
    }
    float* Ginv = xc;
    kgemm_nn64<0><<<dim3(CP / 64, DM / 64), 256, 0, stream>>>(Ginv, Dt32, Et32, nullptr);
    ktrs<<<dim3(DM / 64, CP / 64), 256, 0, stream>>>(Et32, nullptr, EHs, ELs, DM, CP, DM);
    kgemm_nn64<1><<<dim3(CP / 64, BDIM / 64), 256, 0, stream>>>(Y, Dt32, nullptr, AH);
    kgemm_aD<<<dim3(DM / 64, BDIM / 64), 256, 0, stream>>>(Y, G, csum, aD);
    // s0 = -thr everywhere (P0 = 0); clobbers all setup-only aliases (now dead)
    kinit_s<<<(int)((size_t)BDIM * CP / 8 / 256), 256, 0, stream>>>(SH, SL);

    // --- ADMM main loop: 3 streaming kernels per iteration, 2-deep prefetch ---
    for (int it = 0; it < NIT; ++it) {
        kg1f<0><<<512, 256, 0, stream>>>(SH, SL, DHs, DLs, Qp);
        kredf<1><<<BDIM * DM / 1024, 256, 0, stream>>>(Qp, aD, nullptr, QH, QL);
        kg2f<<<640, 256, 0, stream>>>(QH, QL, EHs, ELs, AH, SH, SL);
    }

    // --- finalize: recon = normalize(normalize(z @ Dp) + mean), z = relu(s) ---
    kg1f<1><<<512, 256, 0, stream>>>(SH, SL, DHs, DLs, Qp);
    kredf<0><<<BDIM * DM / 1024, 256, 0, stream>>>(Qp, nullptr, aD, nullptr, nullptr);
    kfinal<<<BDIM, 256, 0, stream>>>(aD, mean, out);
}

// Round 3
// 12773.009 us; speedup vs baseline: 1.1152x; 1.0119x over previous
//
#include <hip/hip_runtime.h>
#include <cstddef>
#include <cstdint>

// Problem constants
#define BDIM  1024        // batch rows
#define DM    512         // embedding dim
#define CREAL 10000       // dictionary atoms
#define CP    10112       // padded atoms = 79*128 = 316*32
#define KSPL  16          // split-K chunks for GEMM1
#define RHOC  5.0f
#define THRC  (0.01f/5.0f)
#define NIT   100
#define NSIT  12

typedef float f32x4 __attribute__((ext_vector_type(4)));
typedef _Float16 f16x8 __attribute__((ext_vector_type(8)));
typedef _Float16 f16x4 __attribute__((ext_vector_type(4)));
typedef unsigned int u32x4 __attribute__((ext_vector_type(4)));

// ---------------- helpers ----------------

// Pair scheme: x ~ h + l/64, h=fp16(x), l=fp16((x-h)*64). GEMM uses 3 terms:
// h*h + (h*2^-6)*l + l*(h*2^-6)  (l*l dropped, ~2^-24 rel).
__device__ __forceinline__ f16x8 scl6(f16x8 v) {
    f16x8 r;
#pragma unroll
    for (int i = 0; i < 8; i++) r[i] = v[i] * (_Float16)0.015625f;  // exact exponent shift
    return r;
}

// |s| on an (h,l) pair is EXACT: flip both signs where h is negative.
__device__ __forceinline__ void absfold(f16x8& h8, f16x8& l8) {
    u32x4 h = __builtin_bit_cast(u32x4, h8);
    u32x4 l = __builtin_bit_cast(u32x4, l8);
    u32x4 m = h & 0x80008000u;
    h8 = __builtin_bit_cast(f16x8, h ^ m);
    l8 = __builtin_bit_cast(f16x8, l ^ m);
}

// relu(s) on an (h,l) pair: zero both where h<=0 (edge err ~2^-24, negligible).
__device__ __forceinline__ void relufold(f16x8& h8, f16x8& l8) {
#pragma unroll
    for (int e = 0; e < 8; e++) {
        bool p = h8[e] > (_Float16)0;
        if (!p) { h8[e] = (_Float16)0; l8[e] = (_Float16)0; }
    }
}

// fragment-swizzled plane index for an A-operand matrix [rows][C]:
//   idx = ((row>>4)*(C>>5) + (col>>5))*512 + (((col>>3)&3)*16 + (row&15))*8 + (col&7)
// so a wave's fragment load for (rowtile, coltile32) is base + lane*8.
__device__ __forceinline__ size_t psidx(int row, int col) {   // C = CP (s-planes)
    return ((size_t)(row >> 4) * (CP >> 5) + (size_t)(col >> 5)) * 512
         + (size_t)((((col >> 3) & 3) * 16 + (row & 15)) * 8 + (col & 7));
}

// async 16B-per-lane global -> LDS DMA (no VGPR transit). LDS dest is the
// WAVE-UNIFORM base; HW adds lane*16. Global src is per-lane.
__device__ __forceinline__ void dma16(const _Float16* g, _Float16* l) {
    __builtin_amdgcn_global_load_lds(
        (const __attribute__((address_space(1))) void*)g,
        (__attribute__((address_space(3))) void*)l, 16, 0, 0);
}

__device__ __forceinline__ float blk_sum256(float v) {
    __shared__ float sb[4];
#pragma unroll
    for (int o = 32; o; o >>= 1) v += __shfl_down(v, o, 64);
    int lane = threadIdx.x & 63, w = threadIdx.x >> 6;
    __syncthreads();
    if (lane == 0) sb[w] = v;
    __syncthreads();
    return sb[0] + sb[1] + sb[2] + sb[3];
}

// txt = normalize(text) per row
__global__ __launch_bounds__(256) void knorm_rows(const float* __restrict__ X,
                                                  float* __restrict__ out) {
    int row = blockIdx.x, t = threadIdx.x;
    int off = row * DM + t * 2;
    float2 v = *(const float2*)(X + off);
    float ss = blk_sum256(v.x * v.x + v.y * v.y);
    float inv = 1.0f / fmaxf(sqrtf(ss), 1e-12f);
    float2 o = {v.x * inv, v.y * inv};
    *(float2*)(out + off) = o;
}

// Y = normalize(normalize(image) - mean) per row
__global__ __launch_bounds__(256) void kprep_Y(const float* __restrict__ img,
                                               const float* __restrict__ mean,
                                               float* __restrict__ Y) {
    int row = blockIdx.x, t = threadIdx.x;
    int off = row * DM + t * 2;
    float2 v = *(const float2*)(img + off);
    float ss = blk_sum256(v.x * v.x + v.y * v.y);
    float inv = 1.0f / fmaxf(sqrtf(ss), 1e-12f);
    float2 mm = *(const float2*)(mean + t * 2);
    float tx = v.x * inv - mm.x, ty = v.y * inv - mm.y;
    float ss2 = blk_sum256(tx * tx + ty * ty);
    float inv2 = 1.0f / fmaxf(sqrtf(ss2), 1e-12f);
    float2 o = {tx * inv2, ty * inv2};
    *(float2*)(Y + off) = o;
}

// transpose (+zero-pad rows>=Rvalid), split to fp16 h/l pair (l stored *64) and write
// the fp16 planes in MFMA FRAGMENT-SWIZZLED order (see psidx formula).
// optional fp32 out = reconstructed pair, ROW-MAJOR.
__global__ __launch_bounds__(256) void ktrs(const float* __restrict__ in,
                                            float* __restrict__ out32,
                                            _Float16* __restrict__ oH,
                                            _Float16* __restrict__ oL,
                                            int Rvalid, int Cin, int Rout) {
    __shared__ float tile[64][65];
    int r0 = blockIdx.x * 64;   // rows of in  (cols of out)
    int c0 = blockIdx.y * 64;   // cols of in  (rows of out)
    int t = threadIdx.x;
    int ri = r0 + (t >> 2);
    int cc = (t & 3) * 16;
#pragma unroll
    for (int q = 0; q < 4; ++q) {
        float4 v = {0.f, 0.f, 0.f, 0.f};
        if (ri < Rvalid) v = *(const float4*)(in + (size_t)ri * Cin + c0 + cc + q * 4);
        *(float4*)&tile[t >> 2][cc + q * 4] = v;
    }
    __syncthreads();
    int oc = c0 + (t >> 2);            // out row
    int orr = r0 + (t & 3) * 16;       // out col base (multiple of 16)
    _Float16 hv[16], lv[16];
#pragma unroll
    for (int q = 0; q < 16; ++q) {
        float v = tile[(t & 3) * 16 + q][t >> 2];
        _Float16 h = (_Float16)v;
        _Float16 l = (_Float16)((v - (float)h) * 64.f);
        hv[q] = h; lv[q] = l;
        if (out32) out32[(size_t)oc * Rout + orr + q] = (float)h + (float)l * 0.015625f;
    }
    int rt = oc >> 4, rin = oc & 15;
    int kt = orr >> 5;
    int kq0 = (orr >> 3) & 3;          // 0 or 2
    size_t base = ((size_t)rt * (Rout >> 5) + kt) * 512;
    *(f16x8*)(oH + base + (size_t)(kq0 * 16 + rin) * 8)       = *(f16x8*)&hv[0];
    *(f16x8*)(oH + base + (size_t)((kq0 + 1) * 16 + rin) * 8) = *(f16x8*)&hv[8];
    *(f16x8*)(oL + base + (size_t)(kq0 * 16 + rin) * 8)       = *(f16x8*)&lv[0];
    *(f16x8*)(oL + base + (size_t)((kq0 + 1) * 16 + rin) * 8) = *(f16x8*)&lv[8];
}

// csum[n] = sum_k Dt[n][k]  (deterministic per-row wave reduce)
__global__ void kcsum(const float* __restrict__ Dt, float* __restrict__ csum) {
    int n = blockIdx.x, t = threadIdx.x;   // 64 threads = 1 wave
    float s = 0.f;
    for (int k = t; k < CP; k += 64) s += Dt[(size_t)n * CP + k];
#pragma unroll
    for (int o = 32; o; o >>= 1) s += __shfl_down(s, o, 64);
    if (t == 0) csum[n] = s;
}

// G = Dt*Dt^T + rho I  (Dt [512][CP] fp32; 64x64 tiles, K=CP)
__global__ __launch_bounds__(256) void kG(const float* __restrict__ Dt,
                                          float* __restrict__ G) {
    __shared__ float As[32][68];
    __shared__ float Bs[32][68];
    int tid = threadIdx.x;
    int j0 = blockIdx.x * 64, i0 = blockIdx.y * 64;
    int tn = (tid & 15) * 4, tm = (tid >> 4) * 4;
    float acc[4][4];
#pragma unroll
    for (int i = 0; i < 4; i++)
#pragma unroll
        for (int j = 0; j < 4; j++) acc[i][j] = 0.f;
    for (int k0 = 0; k0 < CP; k0 += 32) {
        __syncthreads();
#pragma unroll
        for (int p = 0; p < 2; ++p) {
            int idx = tid + p * 256;
            int row = idx >> 3, kv = (idx & 7) << 2;
            float4 va = *(const float4*)(Dt + (size_t)(i0 + row) * CP + k0 + kv);
            As[kv + 0][row] = va.x; As[kv + 1][row] = va.y;
            As[kv + 2][row] = va.z; As[kv + 3][row] = va.w;
            float4 vb = *(const float4*)(Dt + (size_t)(j0 + row) * CP + k0 + kv);
            Bs[kv + 0][row] = vb.x; Bs[kv + 1][row] = vb.y;
            Bs[kv + 2][row] = vb.z; Bs[kv + 3][row] = vb.w;
        }
        __syncthreads();
#pragma unroll
        for (int k = 0; k < 32; ++k) {
            float4 a4 = *(const float4*)&As[k][tm];
            float4 b4 = *(const float4*)&Bs[k][tn];
            float af[4] = {a4.x, a4.y, a4.z, a4.w};
            float bf[4] = {b4.x, b4.y, b4.z, b4.w};
#pragma unroll
            for (int i = 0; i < 4; i++)
#pragma unroll
                for (int j = 0; j < 4; j++) acc[i][j] = fmaf(af[i], bf[j], acc[i][j]);
        }
    }
#pragma unroll
    for (int i = 0; i < 4; i++)
#pragma unroll
        for (int j = 0; j < 4; j++) {
            int gi = i0 + tm + i, gj = j0 + tn + j;
            G[gi * DM + gj] = acc[i][j] + ((gi == gj) ? RHOC : 0.f);
        }
}

__global__ void krow_abssum(const float* __restrict__ G, float* __restrict__ gmax) {
    int row = blockIdx.x, t = threadIdx.x;   // 64 threads = 1 wave
    float s = 0.f;
    for (int j = t; j < DM; j += 64) s += fabsf(G[row * DM + j]);
#pragma unroll
    for (int o = 32; o; o >>= 1) s += __shfl_down(s, o, 64);
    if (t == 0) atomicMax((int*)gmax, __float_as_int(s));
}

__global__ void kinit_X0(const float* __restrict__ gmax, float* __restrict__ X) {
    int idx = blockIdx.x * 256 + threadIdx.x;
    int i = idx >> 9, j = idx & 511;
    X[idx] = (i == j) ? (1.0f / gmax[0]) : 0.0f;
}

// T = G @ X (512^3 NN, 64x64 tiles)
__global__ __launch_bounds__(256) void kgemm_ns_T(const float* __restrict__ G,
                                                  const float* __restrict__ X,
                                                  float* __restrict__ T) {
    __shared__ float As[32][68];
    __shared__ float Bs[32][68];
    int tid = threadIdx.x;
    int n0 = blockIdx.x * 64, m0 = blockIdx.y * 64;
    int tn = (tid & 15) * 4, tm = (tid >> 4) * 4;
    float acc[4][4];
#pragma unroll
    for (int i = 0; i < 4; i++)
#pragma unroll
        for (int j = 0; j < 4; j++) acc[i][j] = 0.f;
    for (int k0 = 0; k0 < DM; k0 += 32) {
        __syncthreads();
#pragma unroll
        for (int p = 0; p < 2; ++p) {
            int idx = tid + p * 256;
            {
                int row = idx >> 3, kv = (idx & 7) << 2;
                float4 v = *(const float4*)(G + (m0 + row) * DM + k0 + kv);
                As[kv + 0][row] = v.x; As[kv + 1][row] = v.y;
                As[kv + 2][row] = v.z; As[kv + 3][row] = v.w;
            }
            {
                int r = idx >> 4, cv = (idx & 15) << 2;
                *(float4*)&Bs[r][cv] = *(const float4*)(X + (k0 + r) * DM + n0 + cv);
            }
        }
        __syncthreads();
#pragma unroll
        for (int k = 0; k < 32; ++k) {
            float4 a4 = *(const float4*)&As[k][tm];
            float4 b4 = *(const float4*)&Bs[k][tn];
            float af[4] = {a4.x, a4.y, a4.z, a4.w};
            float bf[4] = {b4.x, b4.y, b4.z, b4.w};
#pragma unroll
            for (int i = 0; i < 4; i++)
#pragma unroll
                for (int j = 0; j < 4; j++) acc[i][j] = fmaf(af[i], bf[j], acc[i][j]);
        }
    }
#pragma unroll
    for (int i = 0; i < 4; i++) {
        float4 o = {acc[i][0], acc[i][1], acc[i][2], acc[i][3]};
        *(float4*)(T + (m0 + tm + i) * DM + n0 + tn) = o;
    }
}

// Xn = 2*Xo - Xo @ T
__global__ __launch_bounds__(256) void kgemm_ns_X(const float* __restrict__ Xo,
                                                  const float* __restrict__ T,
                                                  float* __restrict__ Xn) {
    __shared__ float As[32][68];
    __shared__ float Bs[32][68];
    int tid = threadIdx.x;
    int n0 = blockIdx.x * 64, m0 = blockIdx.y * 64;
    int tn = (tid & 15) * 4, tm = (tid >> 4) * 4;
    float acc[4][4];
#pragma unroll
    for (int i = 0; i < 4; i++)
#pragma unroll
        for (int j = 0; j < 4; j++) acc[i][j] = 0.f;
    for (int k0 = 0; k0 < DM; k0 += 32) {
        __syncthreads();
#pragma unroll
        for (int p = 0; p < 2; ++p) {
            int idx = tid + p * 256;
            {
                int row = idx >> 3, kv = (idx & 7) << 2;
                float4 v = *(const float4*)(Xo + (m0 + row) * DM + k0 + kv);
                As[kv + 0][row] = v.x; As[kv + 1][row] = v.y;
                As[kv + 2][row] = v.z; As[kv + 3][row] = v.w;
            }
            {
                int r = idx >> 4, cv = (idx & 15) << 2;
                *(float4*)&Bs[r][cv] = *(const float4*)(T + (k0 + r) * DM + n0 + cv);
            }
        }
        __syncthreads();
#pragma unroll
        for (int k = 0; k < 32; ++k) {
            float4 a4 = *(const float4*)&As[k][tm];
            float4 b4 = *(const float4*)&Bs[k][tn];
            float af[4] = {a4.x, a4.y, a4.z, a4.w};
            float bf[4] = {b4.x, b4.y, b4.z, b4.w};
#pragma unroll
            for (int i = 0; i < 4; i++)
#pragma unroll
                for (int j = 0; j < 4; j++) acc[i][j] = fmaf(af[i], bf[j], acc[i][j]);
        }
    }
#pragma unroll
    for (int i = 0; i < 4; i++) {
        int base = (m0 + tm + i) * DM + n0 + tn;
        float4 xo = *(const float4*)(Xo + base);
        float4 o = {2.f * xo.x - acc[i][0], 2.f * xo.y - acc[i][1],
                    2.f * xo.z - acc[i][2], 2.f * xo.w - acc[i][3]};
        *(float4*)(Xn + base) = o;
    }
}

// NN fp32: out[M][CP] = A[M][512] @ B[512][CP]
// MODE 0: store fp32. MODE 1: store a = acc*0.2 as fp16 scaled by 64.
template <int MODE>
__global__ __launch_bounds__(256) void kgemm_nn64(const float* __restrict__ A,
                                                  const float* __restrict__ B,
                                                  float* __restrict__ out32,
                                                  _Float16* __restrict__ oA) {
    __shared__ float As[32][68];
    __shared__ float Bs[32][68];
    int tid = threadIdx.x;
    int n0 = blockIdx.x * 64, m0 = blockIdx.y * 64;
    int tn = (tid & 15) * 4, tm = (tid >> 4) * 4;
    float acc[4][4];
#pragma unroll
    for (int i = 0; i < 4; i++)
#pragma unroll
        for (int j = 0; j < 4; j++) acc[i][j] = 0.f;
    for (int k0 = 0; k0 < DM; k0 += 32) {
        __syncthreads();
#pragma unroll
        for (int p = 0; p < 2; ++p) {
            int idx = tid + p * 256;
            {
                int row = idx >> 3, kv = (idx & 7) << 2;
                float4 v = *(const float4*)(A + (size_t)(m0 + row) * DM + k0 + kv);
                As[kv + 0][row] = v.x; As[kv + 1][row] = v.y;
                As[kv + 2][row] = v.z; As[kv + 3][row] = v.w;
            }
            {
                int r = idx >> 4, cv = (idx & 15) << 2;
                *(float4*)&Bs[r][cv] = *(const float4*)(B + (size_t)(k0 + r) * CP + n0 + cv);
            }
        }
        __syncthreads();
#pragma unroll
        for (int k = 0; k < 32; ++k) {
            float4 a4 = *(const float4*)&As[k][tm];
            float4 b4 = *(const float4*)&Bs[k][tn];
            float af[4] = {a4.x, a4.y, a4.z, a4.w};
            float bf[4] = {b4.x, b4.y, b4.z, b4.w};
#pragma unroll
            for (int i = 0; i < 4; i++)
#pragma unroll
                for (int j = 0; j < 4; j++) acc[i][j] = fmaf(af[i], bf[j], acc[i][j]);
        }
    }
#pragma unroll
    for (int i = 0; i < 4; i++)
#pragma unroll
        for (int j = 0; j < 4; j++) {
            size_t idx = (size_t)(m0 + tm + i) * CP + n0 + tn + j;
            if (MODE == 0) out32[idx] = acc[i][j];
            else           oA[idx] = (_Float16)(acc[i][j] * 0.2f * 64.f);
        }
}

// aD = Y@G/rho - Y - thr*csum   (out [1024][512]; 64x64 tiles, K=512)
// the -thr*csum term folds GEMM1's constant correction: v = |s| - thr.
__global__ __launch_bounds__(256) void kgemm_aD(const float* __restrict__ Yb,
                                                const float* __restrict__ G,
                                                const float* __restrict__ csum,
                                                float* __restrict__ aD) {
    __shared__ float As[32][68];
    __shared__ float Bs[32][68];
    int tid = threadIdx.x;
    int n0 = blockIdx.x * 64, m0 = blockIdx.y * 64;
    int tn = (tid & 15) * 4, tm = (tid >> 4) * 4;
    float acc[4][4];
#pragma unroll
    for (int i = 0; i < 4; i++)
#pragma unroll
        for (int j = 0; j < 4; j++) acc[i][j] = 0.f;
    for (int k0 = 0; k0 < DM; k0 += 32) {
        __syncthreads();
#pragma unroll
        for (int p = 0; p < 2; ++p) {
            int idx = tid + p * 256;
            {
                int row = idx >> 3, kv = (idx & 7) << 2;
                float4 v = *(const float4*)(Yb + (size_t)(m0 + row) * DM + k0 + kv);
                As[kv + 0][row] = v.x; As[kv + 1][row] = v.y;
                As[kv + 2][row] = v.z; As[kv + 3][row] = v.w;
            }
            {
                int r = idx >> 4, cv = (idx & 15) << 2;
                *(float4*)&Bs[r][cv] = *(const float4*)(G + (k0 + r) * DM + n0 + cv);
            }
        }
        __syncthreads();
#pragma unroll
        for (int k = 0; k < 32; ++k) {
            float4 a4 = *(const float4*)&As[k][tm];
            float4 b4 = *(const float4*)&Bs[k][tn];
            float af[4] = {a4.x, a4.y, a4.z, a4.w};
            float bf[4] = {b4.x, b4.y, b4.z, b4.w};
#pragma unroll
            for (int i = 0; i < 4; i++)
#pragma unroll
                for (int j = 0; j < 4; j++) acc[i][j] = fmaf(af[i], bf[j], acc[i][j]);
        }
    }
    float4 c4 = *(const float4*)(csum + n0 + tn);
#pragma unroll
    for (int i = 0; i < 4; i++) {
        int base = (m0 + tm + i) * DM + n0 + tn;
        float4 y4 = *(const float4*)(Yb + base);
        float4 o = {acc[i][0] * 0.2f - y4.x - THRC * c4.x,
                    acc[i][1] * 0.2f - y4.y - THRC * c4.y,
                    acc[i][2] * 0.2f - y4.z - THRC * c4.z,
                    acc[i][3] * 0.2f - y4.w - THRC * c4.w};
        *(float4*)(aD + base) = o;
    }
}

// fill s-planes with the pair of (-thr): s0 = P0 - thr = -thr  (P0 = 0)
__global__ void kinit_s(_Float16* __restrict__ SHp, _Float16* __restrict__ SLp) {
    size_t i = ((size_t)blockIdx.x * 256 + threadIdx.x) * 8;
    _Float16 h = (_Float16)(-THRC);
    _Float16 l = (_Float16)((-THRC - (float)h) * 64.f);
    f16x8 hv, lv;
#pragma unroll
    for (int e = 0; e < 8; e++) { hv[e] = h; lv[e] = l; }
    *(f16x8*)(SHp + i) = hv;
    *(f16x8*)(SLp + i) = lv;
}

// ------- loop kernels: 2-phase template — DMA-staged A (LDS dbuf) + reg-dbuf B -------
// LDS A buffer layout (per buf): [tile 0..7][plane h/l][512 halfs fragment-linear]
// = exact copy of the global fragment blocks -> DMA dest is linear, ds_read is
// lane*16B (conflict-free), and the MFMA A-fragment is *(f16x8*)&sA[tile*1024+plane*512+lane*8].

struct BFrag { f16x8 bh[4], bl[4]; };

__device__ __forceinline__ void bload(BFrag& f,
                                      const _Float16* __restrict__ BH,
                                      const _Float16* __restrict__ BL,
                                      int sp, int ntb, int kt, size_t lo) {
#pragma unroll
    for (int j = 0; j < 4; j++) {
        size_t go = ((size_t)(ntb + j) * kt + sp) * 512 + lo;
        f.bh[j] = *(const f16x8*)(BH + go);
        f.bl[j] = *(const f16x8*)(BL + go);
    }
}

// stage the 16 fragment chunks (8 row-tiles x 2 planes, 1KB each) of A[step sp]
// into LDS buf. 4 waves x 4 chunks. plane select is compile-time (k&1).
__device__ __forceinline__ void stageA(_Float16* __restrict__ sab,
                                       const _Float16* __restrict__ AH,
                                       const _Float16* __restrict__ AL,
                                       int sp, int mtbB, int kt, int wvu, int lane) {
#pragma unroll
    for (int k = 0; k < 4; k++) {
        const int c = wvu * 4 + k;
        const int t = c >> 1;
        const _Float16* gp = ((k & 1) ? AL : AH)
                           + ((size_t)(mtbB + t) * kt + sp) * 512 + (size_t)lane * 8;
        _Float16* lp = sab + (size_t)t * 1024 + (size_t)(k & 1) * 512;
        dma16(gp, lp);
    }
}

// 48-MFMA cluster reading A-fragments from LDS. FOLD: 0=abs, 1=relu, 2=none.
template <int FOLD>
__device__ __forceinline__ void compute_lds(const _Float16* __restrict__ sab,
                                            int wm, int lane, const BFrag& B,
                                            f32x4 (&acc)[4][4]) {
    const int tb = wm >> 4;
    f16x8 ah[4], al[4];
#pragma unroll
    for (int i = 0; i < 4; i++) {
        const _Float16* p = sab + (size_t)(tb + i) * 1024 + (size_t)lane * 8;
        ah[i] = *(const f16x8*)p;
        al[i] = *(const f16x8*)(p + 512);
    }
#pragma unroll
    for (int i = 0; i < 4; i++) {
        if (FOLD == 0) absfold(ah[i], al[i]);
        else if (FOLD == 1) relufold(ah[i], al[i]);
    }
    f16x8 as_[4], bs_[4];
#pragma unroll
    for (int i = 0; i < 4; i++) as_[i] = scl6(ah[i]);
#pragma unroll
    for (int j = 0; j < 4; j++) bs_[j] = scl6(B.bh[j]);
#pragma unroll
    for (int i = 0; i < 4; i++)
#pragma unroll
        for (int j = 0; j < 4; j++) {
            acc[i][j] = __builtin_amdgcn_mfma_f32_16x16x32_f16(ah[i],  B.bh[j], acc[i][j], 0, 0, 0);
            acc[i][j] = __builtin_amdgcn_mfma_f32_16x16x32_f16(as_[i], B.bl[j], acc[i][j], 0, 0, 0);
            acc[i][j] = __builtin_amdgcn_mfma_f32_16x16x32_f16(al[i],  bs_[j],  acc[i][j], 0, 0, 0);
        }
}

// GEMM1 partial: Qp[ks] = op(s) @ Dp over this ks's K-chunk of CP.
// MODE 0 (loop): op = |s| (pair sign-fold; -thr folded into kred via aD').
// MODE 1 (final): op = relu(s) = z.
// XCD map: raw%8 selects a ks-pair. Step counts per ks: 20 (last: 16) — EVEN,
// so the 2-phase pipeline below has no tail.
template <int MODE>
__global__ __launch_bounds__(256, 2) void kg1f(const _Float16* __restrict__ SHp,
                                               const _Float16* __restrict__ SLp,
                                               const _Float16* __restrict__ DHs,
                                               const _Float16* __restrict__ DLs,
                                               float* __restrict__ Qp) {
    __shared__ _Float16 sA[2][8192];   // 32 KB: [buf][tile*1024 + plane*512 + frag]
    const int raw = blockIdx.x;
    const int xcd = raw & 7;
    const int r   = raw >> 3;            // 0..63
    const int ks  = xcd * 2 + (r & 1);   // 0..15
    const int q   = r >> 1;              // 0..31
    const int mb  = q >> 2, nb = q & 3;
    const int n0 = nb * 128, m0 = mb * 128;
    const int tid = threadIdx.x;
    const int lane = tid & 63;
    const int wvu = tid >> 6;
    const int wm = (wvu >> 1) * 64, wn = (wvu & 1) * 64;
    f32x4 acc[4][4] = {};

    const int steps = CP / 32;                    // 316
    const int per = (steps + KSPL - 1) / KSPL;    // 20
    int s0 = ks * per;
    int s1 = s0 + per; if (s1 > steps) s1 = steps;

    const int mtbB = m0 >> 4;          // block A row-tile base
    const int ntb = (n0 + wn) >> 4;    // B fragment row-tile base (DM rows)
    const size_t lo = (size_t)lane * 8;
    const int KT = CP / 32;

    BFrag B0, B1;
    // prologue: stage step s0 into buf0, load B[s0]
    stageA(sA[0], SHp, SLp, s0, mtbB, KT, wvu, lane);
    bload(B0, DHs, DLs, s0, ntb, KT, lo);
    __syncthreads();                   // drain publishes buf0

    for (int sp = s0; sp < s1; sp += 2) {
        // phase A: compute buf0/B0, prefetch sp+1 into buf1/B1
        stageA(sA[1], SHp, SLp, sp + 1, mtbB, KT, wvu, lane);
        bload(B1, DHs, DLs, sp + 1, ntb, KT, lo);
        compute_lds<MODE>(sA[0], wm, lane, B0, acc);
        __syncthreads();
        // phase B: compute buf1/B1, prefetch sp+2 into buf0/B0
        if (sp + 2 < s1) {
            stageA(sA[0], SHp, SLp, sp + 2, mtbB, KT, wvu, lane);
            bload(B0, DHs, DLs, sp + 2, ntb, KT, lo);
        }
        compute_lds<MODE>(sA[1], wm, lane, B1, acc);
        __syncthreads();
    }

    float* outp = Qp + (size_t)ks * (BDIM * DM);
    const int r0 = (lane >> 4) * 4, c0l = lane & 15;
#pragma unroll
    for (int i = 0; i < 4; i++)
#pragma unroll
        for (int v = 0; v < 4; v++) {
            int row = m0 + wm + i * 16 + r0 + v;
#pragma unroll
            for (int j = 0; j < 4; j++)
                outp[(size_t)row * DM + n0 + wn + j * 16 + c0l] = acc[i][j][v];
        }
}

// Qf reduce: ADD=1 (loop): Qf = aD' + sum Qp -> write Qf h/l FRAGMENT PLANES.
//            ADD=0 (final): Qf = sum Qp -> write fp32 row-major to out32.
template <int ADD>
__global__ void kredf(const float* __restrict__ Qp, const float* __restrict__ aD,
                      float* __restrict__ out32, _Float16* __restrict__ QH,
                      _Float16* __restrict__ QL) {
    size_t b = ((size_t)blockIdx.x * 256 + threadIdx.x) * 4;
    float4 s = {0.f, 0.f, 0.f, 0.f};
    if (ADD) s = *(const float4*)(aD + b);
#pragma unroll
    for (int qq = 0; qq < KSPL; qq++) {
        float4 t = *(const float4*)(Qp + (size_t)qq * (BDIM * DM) + b);
        s.x += t.x; s.y += t.y; s.z += t.z; s.w += t.w;
    }
    if (ADD) {
        int row = (int)(b >> 9), col = (int)(b & 511);
        size_t t0 = ((size_t)(row >> 4) * 16 + (size_t)(col >> 5)) * 512
                  + (size_t)((((col >> 3) & 3) * 16 + (row & 15)) * 8 + (col & 7));
        float sv[4] = {s.x, s.y, s.z, s.w};
        f16x4 h4, l4;
#pragma unroll
        for (int e = 0; e < 4; e++) {
            _Float16 h = (_Float16)sv[e];
            h4[e] = h;
            l4[e] = (_Float16)((sv[e] - (float)h) * 64.f);
        }
        *(f16x4*)(QH + t0) = h4;
        *(f16x4*)(QL + t0) = l4;
    } else {
        *(float4*)(out32 + b) = s;
    }
}

// GEMM2: acc = Qf @ E^T (out [1024][CP], K=512), fused ADMM epilogue on s-planes:
//   s_old -> z = relu(s_old); P_new = a + z - acc; s_new = P_new - thr (pair stores).
// A (Qf planes) DMA-staged via LDS dbuf; B (E planes) reg-dbuf. 16 even k-steps.
// XCD map: raw%8 selects the nb-group so all 8 mb-sharers of a B-panel co-reside.
__global__ __launch_bounds__(256, 2) void kg2f(const _Float16* __restrict__ QH,
                                               const _Float16* __restrict__ QL,
                                               const _Float16* __restrict__ EHs,
                                               const _Float16* __restrict__ ELs,
                                               const _Float16* __restrict__ AH,
                                               _Float16* __restrict__ SHp,
                                               _Float16* __restrict__ SLp) {
    __shared__ _Float16 sA[2][8192];
    const int raw = blockIdx.x;
    const int g = raw & 7;
    const int q = raw >> 3;              // 0..79
    const int mb = q & 7, jj = q >> 3;   // jj 0..9
    const int nb = g * 10 + jj;
    if (nb >= 79) return;
    const int n0 = nb * 128, m0 = mb * 128;
    const int tid = threadIdx.x;
    const int lane = tid & 63;
    const int wvu = tid >> 6;
    const int wm = (wvu >> 1) * 64, wn = (wvu & 1) * 64;
    const int mtbB = m0 >> 4;
    const int ntb = (n0 + wn) >> 4;
    const size_t lo = (size_t)lane * 8;
    const int KT = DM / 32;              // 16
    f32x4 acc[4][4] = {};

    BFrag B0, B1;
    stageA(sA[0], QH, QL, 0, mtbB, KT, wvu, lane);
    bload(B0, EHs, ELs, 0, ntb, KT, lo);
    __syncthreads();

    for (int kk = 0; kk < KT; kk += 2) {
        stageA(sA[1], QH, QL, kk + 1, mtbB, KT, wvu, lane);
        bload(B1, EHs, ELs, kk + 1, ntb, KT, lo);
        compute_lds<2>(sA[0], wm, lane, B0, acc);
        __syncthreads();
        if (kk + 2 < KT) {
            stageA(sA[0], QH, QL, kk + 2, mtbB, KT, wvu, lane);
            bload(B0, EHs, ELs, kk + 2, ntb, KT, lo);
        }
        compute_lds<2>(sA[1], wm, lane, B1, acc);
        __syncthreads();
    }

    const int r0 = (lane >> 4) * 4, c0l = lane & 15;
#pragma unroll
    for (int i = 0; i < 4; i++)
#pragma unroll
        for (int v = 0; v < 4; v++) {
            int row = m0 + wm + i * 16 + r0 + v;
#pragma unroll
            for (int j = 0; j < 4; j++) {
                int col = n0 + wn + j * 16 + c0l;
                size_t idx = (size_t)row * CP + col;
                size_t ps = psidx(row, col);
                float a = (float)AH[idx] * 0.015625f;
                float sold = (float)SHp[ps] + (float)SLp[ps] * 0.015625f;
                float z = fmaxf(sold, 0.f);
                float pn = a + z - acc[i][j][v];
                float sn = pn - THRC;
                _Float16 h = (_Float16)sn;
                SHp[ps] = h;
                SLp[ps] = (_Float16)((sn - (float)h) * 64.f);
            }
        }
}

// final: recon = normalize(normalize(Qf) + mean)
__global__ __launch_bounds__(256) void kfinal(const float* __restrict__ Qf,
                                              const float* __restrict__ mean,
                                              float* __restrict__ out) {
    int row = blockIdx.x, t = threadIdx.x;
    int off = row * DM + t * 2;
    float2 qv = *(const float2*)(Qf + off);
    float rx = qv.x, ry = qv.y;
    float ss = blk_sum256(rx * rx + ry * ry);
    float inv = 1.0f / fmaxf(sqrtf(ss), 1e-12f);
    rx *= inv; ry *= inv;
    float2 mm = *(const float2*)(mean + t * 2);
    rx += mm.x; ry += mm.y;
    float ss2 = blk_sum256(rx * rx + ry * ry);
    float inv2 = 1.0f / fmaxf(sqrtf(ss2), 1e-12f);
    float2 o = {rx * inv2, ry * inv2};
    *(float2*)(out + off) = o;
}

extern "C" void kernel_launch(void* const* d_in, const int* in_sizes, int n_in,
                              void* d_out, int out_size, void* d_ws, size_t ws_size,
                              hipStream_t stream) {
    const float* image = (const float*)d_in[0];
    const float* text  = (const float*)d_in[1];
    const float* mean  = (const float*)d_in[2];
    const float* D     = (const float*)d_in[3];
    float* out = (float*)d_out;
    float* ws = (float*)d_ws;

    // ---- workspace layout (float offsets); total 35,324,480 floats = 141.3 MB ----
    const size_t PLH = (size_t)DM * CP;                 // halfs per D/E plane
    float* aD   = ws;                                   // [1024][512] (also final Qf32)
    _Float16* QH = (_Float16*)(ws + 524288);            // Qf h-plane (frag-swizzled)
    _Float16* QL = QH + (size_t)BDIM * DM;              // Qf l-plane
    _Float16* DHs = (_Float16*)(ws + 1048576);          // D planes [DM][CP]
    _Float16* DLs = DHs + PLH;
    _Float16* EHs = DLs + PLH;                          // E planes [CP][DM]
    _Float16* ELs = EHs + PLH;
    _Float16* AH  = ELs + PLH;                          // a*64 fp16 [1024][CP] row-major
    _Float16* SH  = AH + (size_t)BDIM * CP;             // s h-plane (frag-swizzled [1024][CP])
    _Float16* SL  = SH + (size_t)BDIM * CP;             // s l-plane
    float* Qp   = (float*)(SL + (size_t)BDIM * CP);     // KSPL x [1024][512] partials
    float* csum = Qp + (size_t)KSPL * BDIM * DM;        // 512
    float* gmax = csum + 512;                           // 64
    // setup-only aliases (dead before kinit_s fills the s-planes):
    float* Dt32 = (float*)SH;                           // [512][CP] fp32
    float* G    = Dt32 + (size_t)DM * CP;
    float* Xa   = G + 262144;
    float* Xb   = Xa + 262144;
    float* Tns  = Xb + 262144;
    float* Y    = Tns + 262144;
    float* Et32 = (float*)AH;                           // [512][CP] fp32 (pre-AH)

    // --- setup ---
    knorm_rows<<<BDIM, 256, 0, stream>>>(text, out + (size_t)BDIM * DM);
    kprep_Y<<<BDIM, 256, 0, stream>>>(image, mean, Y);
    ktrs<<<dim3(CP / 64, DM / 64), 256, 0, stream>>>(D, Dt32, DHs, DLs, CREAL, DM, CP);
    kcsum<<<DM, 64, 0, stream>>>(Dt32, csum);
    kG<<<dim3(8, 8), 256, 0, stream>>>(Dt32, G);
    (void)hipMemsetAsync(gmax, 0, 4, stream);
    krow_abssum<<<DM, 64, 0, stream>>>(G, gmax);
    kinit_X0<<<DM * DM / 256, 256, 0, stream>>>(gmax, Xa);
    float* xc = Xa;
    float* xn = Xb;
    for (int it = 0; it < NSIT; ++it) {
        kgemm_ns_T<<<dim3(8, 8), 256, 0, stream>>>(G, xc, Tns);
        kgemm_ns_X<<<dim3(8, 8), 256, 0, stream>>>(xc, Tns, xn);
        float* tmp = xc; xc = xn; xn = tmp;
    }
    float* Ginv = xc;
    kgemm_nn64<0><<<dim3(CP / 64, DM / 64), 256, 0, stream>>>(Ginv, Dt32, Et32, nullptr);
    ktrs<<<dim3(DM / 64, CP / 64), 256, 0, stream>>>(Et32, nullptr, EHs, ELs, DM, CP, DM);
    kgemm_nn64<1><<<dim3(CP / 64, BDIM / 64), 256, 0, stream>>>(Y, Dt32, nullptr, AH);
    kgemm_aD<<<dim3(DM / 64, BDIM / 64), 256, 0, stream>>>(Y, G, csum, aD);
    // s0 = -thr everywhere (P0 = 0); clobbers all setup-only aliases (now dead)
    kinit_s<<<(int)((size_t)BDIM * CP / 8 / 256), 256, 0, stream>>>(SH, SL);

    // --- ADMM main loop: 2-phase DMA-staged GEMMs ---
    for (int it = 0; it < NIT; ++it) {
        kg1f<0><<<512, 256, 0, stream>>>(SH, SL, DHs, DLs, Qp);
        kredf<1><<<BDIM * DM / 1024, 256, 0, stream>>>(Qp, aD, nullptr, QH, QL);
        kg2f<<<640, 256, 0, stream>>>(QH, QL, EHs, ELs, AH, SH, SL);
    }

    // --- finalize: recon = normalize(normalize(z @ Dp) + mean), z = relu(s) ---
    kg1f<1><<<512, 256, 0, stream>>>(SH, SL, DHs, DLs, Qp);
    kredf<0><<<BDIM * DM / 1024, 256, 0, stream>>>(Qp, nullptr, aD, nullptr, nullptr);
    kfinal<<<BDIM, 256, 0, stream>>>(aD, mean, out);
}

// Round 4
// 11333.520 us; speedup vs baseline: 1.2568x; 1.1270x over previous
//
#include <hip/hip_runtime.h>
#include <cstddef>
#include <cstdint>

// Problem constants
#define BDIM  1024        // batch rows
#define DM    512         // embedding dim
#define CREAL 10000       // dictionary atoms
#define CP    10112       // padded atoms = 79*128 = 316*32
#define KSPL  16          // split-K chunks for GEMM1
#define RHOC  5.0f
#define THRC  (0.01f/5.0f)
#define NIT   100
#define NSIT  12

typedef float f32x4 __attribute__((ext_vector_type(4)));
typedef _Float16 f16x8 __attribute__((ext_vector_type(8)));
typedef _Float16 f16x4 __attribute__((ext_vector_type(4)));
typedef unsigned int u32x4 __attribute__((ext_vector_type(4)));

// ---------------- helpers ----------------

// Pair scheme: x ~ h + l/64, h=fp16(x), l=fp16((x-h)*64). GEMM uses 3 terms:
// h*h + (h*2^-6)*l + l*(h*2^-6)  (l*l dropped, ~2^-24 rel).
__device__ __forceinline__ f16x8 scl6(f16x8 v) {
    f16x8 r;
#pragma unroll
    for (int i = 0; i < 8; i++) r[i] = v[i] * (_Float16)0.015625f;  // exact exponent shift
    return r;
}

// |s| on an (h,l) pair is EXACT: flip both signs where h is negative.
__device__ __forceinline__ void absfold(f16x8& h8, f16x8& l8) {
    u32x4 h = __builtin_bit_cast(u32x4, h8);
    u32x4 l = __builtin_bit_cast(u32x4, l8);
    u32x4 m = h & 0x80008000u;
    h8 = __builtin_bit_cast(f16x8, h ^ m);
    l8 = __builtin_bit_cast(f16x8, l ^ m);
}

// relu(s) on an (h,l) pair: zero both where h<=0 (edge err ~2^-24, negligible).
__device__ __forceinline__ void relufold(f16x8& h8, f16x8& l8) {
#pragma unroll
    for (int e = 0; e < 8; e++) {
        bool p = h8[e] > (_Float16)0;
        if (!p) { h8[e] = (_Float16)0; l8[e] = (_Float16)0; }
    }
}

// fragment-swizzled plane index for an A-operand matrix [rows][C]:
//   idx = ((row>>4)*(C>>5) + (col>>5))*512 + (((col>>3)&3)*16 + (row&15))*8 + (col&7)
// so a wave's fragment load for (rowtile, coltile32) is base + lane*8.
__device__ __forceinline__ size_t psidx(int row, int col) {   // C = CP (s-planes)
    return ((size_t)(row >> 4) * (CP >> 5) + (size_t)(col >> 5)) * 512
         + (size_t)((((col >> 3) & 3) * 16 + (row & 15)) * 8 + (col & 7));
}

// async 16B-per-lane global -> LDS DMA (no VGPR transit). LDS dest is the
// WAVE-UNIFORM base; HW adds lane*16. Global src is per-lane.
__device__ __forceinline__ void dma16(const _Float16* g, _Float16* l) {
    __builtin_amdgcn_global_load_lds(
        (const __attribute__((address_space(1))) void*)g,
        (__attribute__((address_space(3))) void*)l, 16, 0, 0);
}

__device__ __forceinline__ float blk_sum256(float v) {
    __shared__ float sb[4];
#pragma unroll
    for (int o = 32; o; o >>= 1) v += __shfl_down(v, o, 64);
    int lane = threadIdx.x & 63, w = threadIdx.x >> 6;
    __syncthreads();
    if (lane == 0) sb[w] = v;
    __syncthreads();
    return sb[0] + sb[1] + sb[2] + sb[3];
}

// txt = normalize(text) per row
__global__ __launch_bounds__(256) void knorm_rows(const float* __restrict__ X,
                                                  float* __restrict__ out) {
    int row = blockIdx.x, t = threadIdx.x;
    int off = row * DM + t * 2;
    float2 v = *(const float2*)(X + off);
    float ss = blk_sum256(v.x * v.x + v.y * v.y);
    float inv = 1.0f / fmaxf(sqrtf(ss), 1e-12f);
    float2 o = {v.x * inv, v.y * inv};
    *(float2*)(out + off) = o;
}

// Y = normalize(normalize(image) - mean) per row
__global__ __launch_bounds__(256) void kprep_Y(const float* __restrict__ img,
                                               const float* __restrict__ mean,
                                               float* __restrict__ Y) {
    int row = blockIdx.x, t = threadIdx.x;
    int off = row * DM + t * 2;
    float2 v = *(const float2*)(img + off);
    float ss = blk_sum256(v.x * v.x + v.y * v.y);
    float inv = 1.0f / fmaxf(sqrtf(ss), 1e-12f);
    float2 mm = *(const float2*)(mean + t * 2);
    float tx = v.x * inv - mm.x, ty = v.y * inv - mm.y;
    float ss2 = blk_sum256(tx * tx + ty * ty);
    float inv2 = 1.0f / fmaxf(sqrtf(ss2), 1e-12f);
    float2 o = {tx * inv2, ty * inv2};
    *(float2*)(Y + off) = o;
}

// transpose (+zero-pad rows>=Rvalid), split to fp16 h/l pair (l stored *64) and write
// the fp16 planes in MFMA FRAGMENT-SWIZZLED order (see psidx formula).
// optional fp32 out = reconstructed pair, ROW-MAJOR.
__global__ __launch_bounds__(256) void ktrs(const float* __restrict__ in,
                                            float* __restrict__ out32,
                                            _Float16* __restrict__ oH,
                                            _Float16* __restrict__ oL,
                                            int Rvalid, int Cin, int Rout) {
    __shared__ float tile[64][65];
    int r0 = blockIdx.x * 64;   // rows of in  (cols of out)
    int c0 = blockIdx.y * 64;   // cols of in  (rows of out)
    int t = threadIdx.x;
    int ri = r0 + (t >> 2);
    int cc = (t & 3) * 16;
#pragma unroll
    for (int q = 0; q < 4; ++q) {
        float4 v = {0.f, 0.f, 0.f, 0.f};
        if (ri < Rvalid) v = *(const float4*)(in + (size_t)ri * Cin + c0 + cc + q * 4);
        *(float4*)&tile[t >> 2][cc + q * 4] = v;
    }
    __syncthreads();
    int oc = c0 + (t >> 2);            // out row
    int orr = r0 + (t & 3) * 16;       // out col base (multiple of 16)
    _Float16 hv[16], lv[16];
#pragma unroll
    for (int q = 0; q < 16; ++q) {
        float v = tile[(t & 3) * 16 + q][t >> 2];
        _Float16 h = (_Float16)v;
        _Float16 l = (_Float16)((v - (float)h) * 64.f);
        hv[q] = h; lv[q] = l;
        if (out32) out32[(size_t)oc * Rout + orr + q] = (float)h + (float)l * 0.015625f;
    }
    int rt = oc >> 4, rin = oc & 15;
    int kt = orr >> 5;
    int kq0 = (orr >> 3) & 3;          // 0 or 2
    size_t base = ((size_t)rt * (Rout >> 5) + kt) * 512;
    *(f16x8*)(oH + base + (size_t)(kq0 * 16 + rin) * 8)       = *(f16x8*)&hv[0];
    *(f16x8*)(oH + base + (size_t)((kq0 + 1) * 16 + rin) * 8) = *(f16x8*)&hv[8];
    *(f16x8*)(oL + base + (size_t)(kq0 * 16 + rin) * 8)       = *(f16x8*)&lv[0];
    *(f16x8*)(oL + base + (size_t)((kq0 + 1) * 16 + rin) * 8) = *(f16x8*)&lv[8];
}

// csum[n] = sum_k Dt[n][k]  (deterministic per-row wave reduce)
__global__ void kcsum(const float* __restrict__ Dt, float* __restrict__ csum) {
    int n = blockIdx.x, t = threadIdx.x;   // 64 threads = 1 wave
    float s = 0.f;
    for (int k = t; k < CP; k += 64) s += Dt[(size_t)n * CP + k];
#pragma unroll
    for (int o = 32; o; o >>= 1) s += __shfl_down(s, o, 64);
    if (t == 0) csum[n] = s;
}

// G = Dt*Dt^T + rho I  (Dt [512][CP] fp32; 64x64 tiles, K=CP)
__global__ __launch_bounds__(256) void kG(const float* __restrict__ Dt,
                                          float* __restrict__ G) {
    __shared__ float As[32][68];
    __shared__ float Bs[32][68];
    int tid = threadIdx.x;
    int j0 = blockIdx.x * 64, i0 = blockIdx.y * 64;
    int tn = (tid & 15) * 4, tm = (tid >> 4) * 4;
    float acc[4][4];
#pragma unroll
    for (int i = 0; i < 4; i++)
#pragma unroll
        for (int j = 0; j < 4; j++) acc[i][j] = 0.f;
    for (int k0 = 0; k0 < CP; k0 += 32) {
        __syncthreads();
#pragma unroll
        for (int p = 0; p < 2; ++p) {
            int idx = tid + p * 256;
            int row = idx >> 3, kv = (idx & 7) << 2;
            float4 va = *(const float4*)(Dt + (size_t)(i0 + row) * CP + k0 + kv);
            As[kv + 0][row] = va.x; As[kv + 1][row] = va.y;
            As[kv + 2][row] = va.z; As[kv + 3][row] = va.w;
            float4 vb = *(const float4*)(Dt + (size_t)(j0 + row) * CP + k0 + kv);
            Bs[kv + 0][row] = vb.x; Bs[kv + 1][row] = vb.y;
            Bs[kv + 2][row] = vb.z; Bs[kv + 3][row] = vb.w;
        }
        __syncthreads();
#pragma unroll
        for (int k = 0; k < 32; ++k) {
            float4 a4 = *(const float4*)&As[k][tm];
            float4 b4 = *(const float4*)&Bs[k][tn];
            float af[4] = {a4.x, a4.y, a4.z, a4.w};
            float bf[4] = {b4.x, b4.y, b4.z, b4.w};
#pragma unroll
            for (int i = 0; i < 4; i++)
#pragma unroll
                for (int j = 0; j < 4; j++) acc[i][j] = fmaf(af[i], bf[j], acc[i][j]);
        }
    }
#pragma unroll
    for (int i = 0; i < 4; i++)
#pragma unroll
        for (int j = 0; j < 4; j++) {
            int gi = i0 + tm + i, gj = j0 + tn + j;
            G[gi * DM + gj] = acc[i][j] + ((gi == gj) ? RHOC : 0.f);
        }
}

__global__ void krow_abssum(const float* __restrict__ G, float* __restrict__ gmax) {
    int row = blockIdx.x, t = threadIdx.x;   // 64 threads = 1 wave
    float s = 0.f;
    for (int j = t; j < DM; j += 64) s += fabsf(G[row * DM + j]);
#pragma unroll
    for (int o = 32; o; o >>= 1) s += __shfl_down(s, o, 64);
    if (t == 0) atomicMax((int*)gmax, __float_as_int(s));
}

__global__ void kinit_X0(const float* __restrict__ gmax, float* __restrict__ X) {
    int idx = blockIdx.x * 256 + threadIdx.x;
    int i = idx >> 9, j = idx & 511;
    X[idx] = (i == j) ? (1.0f / gmax[0]) : 0.0f;
}

// T = G @ X (512^3 NN, 64x64 tiles)
__global__ __launch_bounds__(256) void kgemm_ns_T(const float* __restrict__ G,
                                                  const float* __restrict__ X,
                                                  float* __restrict__ T) {
    __shared__ float As[32][68];
    __shared__ float Bs[32][68];
    int tid = threadIdx.x;
    int n0 = blockIdx.x * 64, m0 = blockIdx.y * 64;
    int tn = (tid & 15) * 4, tm = (tid >> 4) * 4;
    float acc[4][4];
#pragma unroll
    for (int i = 0; i < 4; i++)
#pragma unroll
        for (int j = 0; j < 4; j++) acc[i][j] = 0.f;
    for (int k0 = 0; k0 < DM; k0 += 32) {
        __syncthreads();
#pragma unroll
        for (int p = 0; p < 2; ++p) {
            int idx = tid + p * 256;
            {
                int row = idx >> 3, kv = (idx & 7) << 2;
                float4 v = *(const float4*)(G + (m0 + row) * DM + k0 + kv);
                As[kv + 0][row] = v.x; As[kv + 1][row] = v.y;
                As[kv + 2][row] = v.z; As[kv + 3][row] = v.w;
            }
            {
                int r = idx >> 4, cv = (idx & 15) << 2;
                *(float4*)&Bs[r][cv] = *(const float4*)(X + (k0 + r) * DM + n0 + cv);
            }
        }
        __syncthreads();
#pragma unroll
        for (int k = 0; k < 32; ++k) {
            float4 a4 = *(const float4*)&As[k][tm];
            float4 b4 = *(const float4*)&Bs[k][tn];
            float af[4] = {a4.x, a4.y, a4.z, a4.w};
            float bf[4] = {b4.x, b4.y, b4.z, b4.w};
#pragma unroll
            for (int i = 0; i < 4; i++)
#pragma unroll
                for (int j = 0; j < 4; j++) acc[i][j] = fmaf(af[i], bf[j], acc[i][j]);
        }
    }
#pragma unroll
    for (int i = 0; i < 4; i++) {
        float4 o = {acc[i][0], acc[i][1], acc[i][2], acc[i][3]};
        *(float4*)(T + (m0 + tm + i) * DM + n0 + tn) = o;
    }
}

// Xn = 2*Xo - Xo @ T
__global__ __launch_bounds__(256) void kgemm_ns_X(const float* __restrict__ Xo,
                                                  const float* __restrict__ T,
                                                  float* __restrict__ Xn) {
    __shared__ float As[32][68];
    __shared__ float Bs[32][68];
    int tid = threadIdx.x;
    int n0 = blockIdx.x * 64, m0 = blockIdx.y * 64;
    int tn = (tid & 15) * 4, tm = (tid >> 4) * 4;
    float acc[4][4];
#pragma unroll
    for (int i = 0; i < 4; i++)
#pragma unroll
        for (int j = 0; j < 4; j++) acc[i][j] = 0.f;
    for (int k0 = 0; k0 < DM; k0 += 32) {
        __syncthreads();
#pragma unroll
        for (int p = 0; p < 2; ++p) {
            int idx = tid + p * 256;
            {
                int row = idx >> 3, kv = (idx & 7) << 2;
                float4 v = *(const float4*)(Xo + (m0 + row) * DM + k0 + kv);
                As[kv + 0][row] = v.x; As[kv + 1][row] = v.y;
                As[kv + 2][row] = v.z; As[kv + 3][row] = v.w;
            }
            {
                int r = idx >> 4, cv = (idx & 15) << 2;
                *(float4*)&Bs[r][cv] = *(const float4*)(T + (k0 + r) * DM + n0 + cv);
            }
        }
        __syncthreads();
#pragma unroll
        for (int k = 0; k < 32; ++k) {
            float4 a4 = *(const float4*)&As[k][tm];
            float4 b4 = *(const float4*)&Bs[k][tn];
            float af[4] = {a4.x, a4.y, a4.z, a4.w};
            float bf[4] = {b4.x, b4.y, b4.z, b4.w};
#pragma unroll
            for (int i = 0; i < 4; i++)
#pragma unroll
                for (int j = 0; j < 4; j++) acc[i][j] = fmaf(af[i], bf[j], acc[i][j]);
        }
    }
#pragma unroll
    for (int i = 0; i < 4; i++) {
        int base = (m0 + tm + i) * DM + n0 + tn;
        float4 xo = *(const float4*)(Xo + base);
        float4 o = {2.f * xo.x - acc[i][0], 2.f * xo.y - acc[i][1],
                    2.f * xo.z - acc[i][2], 2.f * xo.w - acc[i][3]};
        *(float4*)(Xn + base) = o;
    }
}

// NN fp32: out[M][CP] = A[M][512] @ B[512][CP]
// MODE 0: store fp32. MODE 1: store a = acc*0.2 as fp16 scaled by 64.
template <int MODE>
__global__ __launch_bounds__(256) void kgemm_nn64(const float* __restrict__ A,
                                                  const float* __restrict__ B,
                                                  float* __restrict__ out32,
                                                  _Float16* __restrict__ oA) {
    __shared__ float As[32][68];
    __shared__ float Bs[32][68];
    int tid = threadIdx.x;
    int n0 = blockIdx.x * 64, m0 = blockIdx.y * 64;
    int tn = (tid & 15) * 4, tm = (tid >> 4) * 4;
    float acc[4][4];
#pragma unroll
    for (int i = 0; i < 4; i++)
#pragma unroll
        for (int j = 0; j < 4; j++) acc[i][j] = 0.f;
    for (int k0 = 0; k0 < DM; k0 += 32) {
        __syncthreads();
#pragma unroll
        for (int p = 0; p < 2; ++p) {
            int idx = tid + p * 256;
            {
                int row = idx >> 3, kv = (idx & 7) << 2;
                float4 v = *(const float4*)(A + (size_t)(m0 + row) * DM + k0 + kv);
                As[kv + 0][row] = v.x; As[kv + 1][row] = v.y;
                As[kv + 2][row] = v.z; As[kv + 3][row] = v.w;
            }
            {
                int r = idx >> 4, cv = (idx & 15) << 2;
                *(float4*)&Bs[r][cv] = *(const float4*)(B + (size_t)(k0 + r) * CP + n0 + cv);
            }
        }
        __syncthreads();
#pragma unroll
        for (int k = 0; k < 32; ++k) {
            float4 a4 = *(const float4*)&As[k][tm];
            float4 b4 = *(const float4*)&Bs[k][tn];
            float af[4] = {a4.x, a4.y, a4.z, a4.w};
            float bf[4] = {b4.x, b4.y, b4.z, b4.w};
#pragma unroll
            for (int i = 0; i < 4; i++)
#pragma unroll
                for (int j = 0; j < 4; j++) acc[i][j] = fmaf(af[i], bf[j], acc[i][j]);
        }
    }
#pragma unroll
    for (int i = 0; i < 4; i++)
#pragma unroll
        for (int j = 0; j < 4; j++) {
            size_t idx = (size_t)(m0 + tm + i) * CP + n0 + tn + j;
            if (MODE == 0) out32[idx] = acc[i][j];
            else           oA[idx] = (_Float16)(acc[i][j] * 0.2f * 64.f);
        }
}

// aD = Y@G/rho - Y - thr*csum   (out [1024][512]; 64x64 tiles, K=512)
// the -thr*csum term folds GEMM1's constant correction: v = |s| - thr.
__global__ __launch_bounds__(256) void kgemm_aD(const float* __restrict__ Yb,
                                                const float* __restrict__ G,
                                                const float* __restrict__ csum,
                                                float* __restrict__ aD) {
    __shared__ float As[32][68];
    __shared__ float Bs[32][68];
    int tid = threadIdx.x;
    int n0 = blockIdx.x * 64, m0 = blockIdx.y * 64;
    int tn = (tid & 15) * 4, tm = (tid >> 4) * 4;
    float acc[4][4];
#pragma unroll
    for (int i = 0; i < 4; i++)
#pragma unroll
        for (int j = 0; j < 4; j++) acc[i][j] = 0.f;
    for (int k0 = 0; k0 < DM; k0 += 32) {
        __syncthreads();
#pragma unroll
        for (int p = 0; p < 2; ++p) {
            int idx = tid + p * 256;
            {
                int row = idx >> 3, kv = (idx & 7) << 2;
                float4 v = *(const float4*)(Yb + (size_t)(m0 + row) * DM + k0 + kv);
                As[kv + 0][row] = v.x; As[kv + 1][row] = v.y;
                As[kv + 2][row] = v.z; As[kv + 3][row] = v.w;
            }
            {
                int r = idx >> 4, cv = (idx & 15) << 2;
                *(float4*)&Bs[r][cv] = *(const float4*)(G + (k0 + r) * DM + n0 + cv);
            }
        }
        __syncthreads();
#pragma unroll
        for (int k = 0; k < 32; ++k) {
            float4 a4 = *(const float4*)&As[k][tm];
            float4 b4 = *(const float4*)&Bs[k][tn];
            float af[4] = {a4.x, a4.y, a4.z, a4.w};
            float bf[4] = {b4.x, b4.y, b4.z, b4.w};
#pragma unroll
            for (int i = 0; i < 4; i++)
#pragma unroll
                for (int j = 0; j < 4; j++) acc[i][j] = fmaf(af[i], bf[j], acc[i][j]);
        }
    }
    float4 c4 = *(const float4*)(csum + n0 + tn);
#pragma unroll
    for (int i = 0; i < 4; i++) {
        int base = (m0 + tm + i) * DM + n0 + tn;
        float4 y4 = *(const float4*)(Yb + base);
        float4 o = {acc[i][0] * 0.2f - y4.x - THRC * c4.x,
                    acc[i][1] * 0.2f - y4.y - THRC * c4.y,
                    acc[i][2] * 0.2f - y4.z - THRC * c4.z,
                    acc[i][3] * 0.2f - y4.w - THRC * c4.w};
        *(float4*)(aD + base) = o;
    }
}

// fill s-planes with the pair of (-thr): s0 = P0 - thr = -thr  (P0 = 0)
__global__ void kinit_s(_Float16* __restrict__ SHp, _Float16* __restrict__ SLp) {
    size_t i = ((size_t)blockIdx.x * 256 + threadIdx.x) * 8;
    _Float16 h = (_Float16)(-THRC);
    _Float16 l = (_Float16)((-THRC - (float)h) * 64.f);
    f16x8 hv, lv;
#pragma unroll
    for (int e = 0; e < 8; e++) { hv[e] = h; lv[e] = l; }
    *(f16x8*)(SHp + i) = hv;
    *(f16x8*)(SLp + i) = lv;
}

// ------- loop kernels: 8-wave blocks, BOTH operands DMA-staged (LDS dbuf) -------
// LDS buf layout (32 KB): A chunks c=0..15 at c*512 halfs (tile t=c>>1, plane c&1),
// B chunks at 8192 + (t*2+p)*512. All fragment-linear -> DMA dest linear,
// ds_read = lane*16B (conflict-free).

__device__ __forceinline__ void stage2(_Float16* __restrict__ sab,
                                       const _Float16* __restrict__ AHp,
                                       const _Float16* __restrict__ ALp,
                                       const _Float16* __restrict__ BHp,
                                       const _Float16* __restrict__ BLp,
                                       int sp, int mtbB, int ntbB, int ktA, int ktB,
                                       int wvu, int lane) {
#pragma unroll
    for (int k = 0; k < 4; ++k) {
        const int c = wvu * 4 + k;       // 0..31 (A: 0..15, B: 16..31); wave-uniform side
        const int t = (c >> 1) & 7;
        const int p = c & 1;
        const _Float16* gp;
        if (c < 16) gp = (p ? ALp : AHp) + ((size_t)(mtbB + t) * ktA + sp) * 512 + (size_t)lane * 8;
        else        gp = (p ? BLp : BHp) + ((size_t)(ntbB + t) * ktB + sp) * 512 + (size_t)lane * 8;
        dma16(gp, sab + (size_t)c * 512);
    }
}

// 24-MFMA cluster for a 64x32 wave tile. FOLD: 0=abs, 1=relu, 2=none.
template <int FOLD>
__device__ __forceinline__ void compute8(const _Float16* __restrict__ sab,
                                         int wm, int wn, int lane,
                                         f32x4 (&acc)[4][2]) {
    const int ta = wm >> 4;      // 0 or 4
    const int tb = wn >> 4;      // 0,2,4,6
    f16x8 bh[2], bl[2], bs_[2];
#pragma unroll
    for (int j = 0; j < 2; ++j) {
        const _Float16* p = sab + 8192 + (size_t)(tb + j) * 1024 + (size_t)lane * 8;
        bh[j] = *(const f16x8*)p;
        bl[j] = *(const f16x8*)(p + 512);
        bs_[j] = scl6(bh[j]);
    }
    f16x8 ah[4], al[4], as_[4];
#pragma unroll
    for (int i = 0; i < 4; ++i) {
        const _Float16* p = sab + (size_t)(ta + i) * 1024 + (size_t)lane * 8;
        ah[i] = *(const f16x8*)p;
        al[i] = *(const f16x8*)(p + 512);
    }
#pragma unroll
    for (int i = 0; i < 4; ++i) {
        if (FOLD == 0) absfold(ah[i], al[i]);
        else if (FOLD == 1) relufold(ah[i], al[i]);
        as_[i] = scl6(ah[i]);
    }
#pragma unroll
    for (int i = 0; i < 4; ++i)
#pragma unroll
        for (int j = 0; j < 2; ++j) {
            acc[i][j] = __builtin_amdgcn_mfma_f32_16x16x32_f16(ah[i],  bh[j], acc[i][j], 0, 0, 0);
            acc[i][j] = __builtin_amdgcn_mfma_f32_16x16x32_f16(as_[i], bl[j], acc[i][j], 0, 0, 0);
            acc[i][j] = __builtin_amdgcn_mfma_f32_16x16x32_f16(al[i],  bs_[j], acc[i][j], 0, 0, 0);
        }
}

// GEMM1 partial: Qp[ks] = op(s) @ Dp over this ks's K-chunk of CP.
// MODE 0 (loop): op = |s|; MODE 1 (final): op = relu(s).
// 512 blocks x 512 thr (8 waves, 2M x 4N of 64x32 tiles) = exactly 2 blocks/CU.
template <int MODE>
__global__ __launch_bounds__(512, 4) void kg1f(const _Float16* __restrict__ SHp,
                                               const _Float16* __restrict__ SLp,
                                               const _Float16* __restrict__ DHs,
                                               const _Float16* __restrict__ DLs,
                                               float* __restrict__ Qp) {
    __shared__ _Float16 sAB[2][16384];   // 2 x 32 KB
    const int raw = blockIdx.x;
    const int xcd = raw & 7;
    const int r   = raw >> 3;            // 0..63
    const int ks  = xcd * 2 + (r & 1);   // 0..15
    const int q   = r >> 1;              // 0..31
    const int mb  = q >> 2, nb = q & 3;
    const int n0 = nb * 128, m0 = mb * 128;
    const int tid = threadIdx.x;
    const int lane = tid & 63;
    const int wvu = tid >> 6;            // 0..7
    const int wm = (wvu >> 2) * 64;      // 0,64
    const int wn = (wvu & 3) * 32;       // 0,32,64,96
    f32x4 acc[4][2] = {};

    const int steps = CP / 32;                    // 316
    const int per = (steps + KSPL - 1) / KSPL;    // 20
    int s0 = ks * per;
    int s1 = s0 + per; if (s1 > steps) s1 = steps;

    const int mtbB = m0 >> 4;
    const int ntbB = n0 >> 4;
    const int KT = CP / 32;

    stage2(sAB[0], SHp, SLp, DHs, DLs, s0, mtbB, ntbB, KT, KT, wvu, lane);
    __syncthreads();

    for (int sp = s0; sp < s1; sp += 2) {
        stage2(sAB[1], SHp, SLp, DHs, DLs, sp + 1, mtbB, ntbB, KT, KT, wvu, lane);
        compute8<MODE>(sAB[0], wm, wn, lane, acc);
        __syncthreads();
        if (sp + 2 < s1)
            stage2(sAB[0], SHp, SLp, DHs, DLs, sp + 2, mtbB, ntbB, KT, KT, wvu, lane);
        compute8<MODE>(sAB[1], wm, wn, lane, acc);
        __syncthreads();
    }

    float* outp = Qp + (size_t)ks * (BDIM * DM);
    const int r0 = (lane >> 4) * 4, c0l = lane & 15;
#pragma unroll
    for (int i = 0; i < 4; i++)
#pragma unroll
        for (int v = 0; v < 4; v++) {
            int row = m0 + wm + i * 16 + r0 + v;
#pragma unroll
            for (int j = 0; j < 2; j++)
                outp[(size_t)row * DM + n0 + wn + j * 16 + c0l] = acc[i][j][v];
        }
}

// Qf reduce: ADD=1 (loop): Qf = aD' + sum Qp -> write Qf h/l FRAGMENT PLANES.
//            ADD=0 (final): Qf = sum Qp -> write fp32 row-major to out32.
template <int ADD>
__global__ void kredf(const float* __restrict__ Qp, const float* __restrict__ aD,
                      float* __restrict__ out32, _Float16* __restrict__ QH,
                      _Float16* __restrict__ QL) {
    size_t b = ((size_t)blockIdx.x * 256 + threadIdx.x) * 4;
    float4 s = {0.f, 0.f, 0.f, 0.f};
    if (ADD) s = *(const float4*)(aD + b);
#pragma unroll
    for (int qq = 0; qq < KSPL; qq++) {
        float4 t = *(const float4*)(Qp + (size_t)qq * (BDIM * DM) + b);
        s.x += t.x; s.y += t.y; s.z += t.z; s.w += t.w;
    }
    if (ADD) {
        int row = (int)(b >> 9), col = (int)(b & 511);
        size_t t0 = ((size_t)(row >> 4) * 16 + (size_t)(col >> 5)) * 512
                  + (size_t)((((col >> 3) & 3) * 16 + (row & 15)) * 8 + (col & 7));
        float sv[4] = {s.x, s.y, s.z, s.w};
        f16x4 h4, l4;
#pragma unroll
        for (int e = 0; e < 4; e++) {
            _Float16 h = (_Float16)sv[e];
            h4[e] = h;
            l4[e] = (_Float16)((sv[e] - (float)h) * 64.f);
        }
        *(f16x4*)(QH + t0) = h4;
        *(f16x4*)(QL + t0) = l4;
    } else {
        *(float4*)(out32 + b) = s;
    }
}

// GEMM2: acc = Qf @ E^T (out [1024][CP], K=512), fused ADMM epilogue on s-planes:
//   s_old -> z = relu(s_old); P_new = a + z - acc; s_new = P_new - thr (pair stores).
// 8-wave blocks, both operands DMA-staged. 16 even k-steps.
__global__ __launch_bounds__(512, 4) void kg2f(const _Float16* __restrict__ QH,
                                               const _Float16* __restrict__ QL,
                                               const _Float16* __restrict__ EHs,
                                               const _Float16* __restrict__ ELs,
                                               const _Float16* __restrict__ AH,
                                               _Float16* __restrict__ SHp,
                                               _Float16* __restrict__ SLp) {
    __shared__ _Float16 sAB[2][16384];
    const int raw = blockIdx.x;
    const int g = raw & 7;
    const int q = raw >> 3;              // 0..79
    const int mb = q & 7, jj = q >> 3;   // jj 0..9
    const int nb = g * 10 + jj;
    if (nb >= 79) return;
    const int n0 = nb * 128, m0 = mb * 128;
    const int tid = threadIdx.x;
    const int lane = tid & 63;
    const int wvu = tid >> 6;
    const int wm = (wvu >> 2) * 64;
    const int wn = (wvu & 3) * 32;
    const int mtbB = m0 >> 4;
    const int ntbB = n0 >> 4;
    const int KT = DM / 32;              // 16
    f32x4 acc[4][2] = {};

    stage2(sAB[0], QH, QL, EHs, ELs, 0, mtbB, ntbB, KT, KT, wvu, lane);
    __syncthreads();

    for (int kk = 0; kk < KT; kk += 2) {
        stage2(sAB[1], QH, QL, EHs, ELs, kk + 1, mtbB, ntbB, KT, KT, wvu, lane);
        compute8<2>(sAB[0], wm, wn, lane, acc);
        __syncthreads();
        if (kk + 2 < KT)
            stage2(sAB[0], QH, QL, EHs, ELs, kk + 2, mtbB, ntbB, KT, KT, wvu, lane);
        compute8<2>(sAB[1], wm, wn, lane, acc);
        __syncthreads();
    }

    const int r0 = (lane >> 4) * 4, c0l = lane & 15;
#pragma unroll
    for (int i = 0; i < 4; i++)
#pragma unroll
        for (int v = 0; v < 4; v++) {
            int row = m0 + wm + i * 16 + r0 + v;
#pragma unroll
            for (int j = 0; j < 2; j++) {
                int col = n0 + wn + j * 16 + c0l;
                size_t idx = (size_t)row * CP + col;
                size_t ps = psidx(row, col);
                float a = (float)AH[idx] * 0.015625f;
                float sold = (float)SHp[ps] + (float)SLp[ps] * 0.015625f;
                float z = fmaxf(sold, 0.f);
                float pn = a + z - acc[i][j][v];
                float sn = pn - THRC;
                _Float16 h = (_Float16)sn;
                SHp[ps] = h;
                SLp[ps] = (_Float16)((sn - (float)h) * 64.f);
            }
        }
}

// final: recon = normalize(normalize(Qf) + mean)
__global__ __launch_bounds__(256) void kfinal(const float* __restrict__ Qf,
                                              const float* __restrict__ mean,
                                              float* __restrict__ out) {
    int row = blockIdx.x, t = threadIdx.x;
    int off = row * DM + t * 2;
    float2 qv = *(const float2*)(Qf + off);
    float rx = qv.x, ry = qv.y;
    float ss = blk_sum256(rx * rx + ry * ry);
    float inv = 1.0f / fmaxf(sqrtf(ss), 1e-12f);
    rx *= inv; ry *= inv;
    float2 mm = *(const float2*)(mean + t * 2);
    rx += mm.x; ry += mm.y;
    float ss2 = blk_sum256(rx * rx + ry * ry);
    float inv2 = 1.0f / fmaxf(sqrtf(ss2), 1e-12f);
    float2 o = {rx * inv2, ry * inv2};
    *(float2*)(out + off) = o;
}

extern "C" void kernel_launch(void* const* d_in, const int* in_sizes, int n_in,
                              void* d_out, int out_size, void* d_ws, size_t ws_size,
                              hipStream_t stream) {
    const float* image = (const float*)d_in[0];
    const float* text  = (const float*)d_in[1];
    const float* mean  = (const float*)d_in[2];
    const float* D     = (const float*)d_in[3];
    float* out = (float*)d_out;
    float* ws = (float*)d_ws;

    // ---- workspace layout (float offsets); total 35,324,480 floats = 141.3 MB ----
    const size_t PLH = (size_t)DM * CP;                 // halfs per D/E plane
    float* aD   = ws;                                   // [1024][512] (also final Qf32)
    _Float16* QH = (_Float16*)(ws + 524288);            // Qf h-plane (frag-swizzled)
    _Float16* QL = QH + (size_t)BDIM * DM;              // Qf l-plane
    _Float16* DHs = (_Float16*)(ws + 1048576);          // D planes [DM][CP]
    _Float16* DLs = DHs + PLH;
    _Float16* EHs = DLs + PLH;                          // E planes [CP][DM]
    _Float16* ELs = EHs + PLH;
    _Float16* AH  = ELs + PLH;                          // a*64 fp16 [1024][CP] row-major
    _Float16* SH  = AH + (size_t)BDIM * CP;             // s h-plane (frag-swizzled [1024][CP])
    _Float16* SL  = SH + (size_t)BDIM * CP;             // s l-plane
    float* Qp   = (float*)(SL + (size_t)BDIM * CP);     // KSPL x [1024][512] partials
    float* csum = Qp + (size_t)KSPL * BDIM * DM;        // 512
    float* gmax = csum + 512;                           // 64
    // setup-only aliases (dead before kinit_s fills the s-planes):
    float* Dt32 = (float*)SH;                           // [512][CP] fp32
    float* G    = Dt32 + (size_t)DM * CP;
    float* Xa   = G + 262144;
    float* Xb   = Xa + 262144;
    float* Tns  = Xb + 262144;
    float* Y    = Tns + 262144;
    float* Et32 = (float*)AH;                           // [512][CP] fp32 (pre-AH)

    // --- setup ---
    knorm_rows<<<BDIM, 256, 0, stream>>>(text, out + (size_t)BDIM * DM);
    kprep_Y<<<BDIM, 256, 0, stream>>>(image, mean, Y);
    ktrs<<<dim3(CP / 64, DM / 64), 256, 0, stream>>>(D, Dt32, DHs, DLs, CREAL, DM, CP);
    kcsum<<<DM, 64, 0, stream>>>(Dt32, csum);
    kG<<<dim3(8, 8), 256, 0, stream>>>(Dt32, G);
    (void)hipMemsetAsync(gmax, 0, 4, stream);
    krow_abssum<<<DM, 64, 0, stream>>>(G, gmax);
    kinit_X0<<<DM * DM / 256, 256, 0, stream>>>(gmax, Xa);
    float* xc = Xa;
    float* xn = Xb;
    for (int it = 0; it < NSIT; ++it) {
        kgemm_ns_T<<<dim3(8, 8), 256, 0, stream>>>(G, xc, Tns);
        kgemm_ns_X<<<dim3(8, 8), 256, 0, stream>>>(xc, Tns, xn);
        float* tmp = xc; xc = xn; xn = tmp;
    }
    float* Ginv = xc;
    kgemm_nn64<0><<<dim3(CP / 64, DM / 64), 256, 0, stream>>>(Ginv, Dt32, Et32, nullptr);
    ktrs<<<dim3(DM / 64, CP / 64), 256, 0, stream>>>(Et32, nullptr, EHs, ELs, DM, CP, DM);
    kgemm_nn64<1><<<dim3(CP / 64, BDIM / 64), 256, 0, stream>>>(Y, Dt32, nullptr, AH);
    kgemm_aD<<<dim3(DM / 64, BDIM / 64), 256, 0, stream>>>(Y, G, csum, aD);
    // s0 = -thr everywhere (P0 = 0); clobbers all setup-only aliases (now dead)
    kinit_s<<<(int)((size_t)BDIM * CP / 8 / 256), 256, 0, stream>>>(SH, SL);

    // --- ADMM main loop: 8-wave DMA-staged GEMMs at 16 waves/CU ---
    for (int it = 0; it < NIT; ++it) {
        kg1f<0><<<512, 512, 0, stream>>>(SH, SL, DHs, DLs, Qp);
        kredf<1><<<BDIM * DM / 1024, 256, 0, stream>>>(Qp, aD, nullptr, QH, QL);
        kg2f<<<640, 512, 0, stream>>>(QH, QL, EHs, ELs, AH, SH, SL);
    }

    // --- finalize: recon = normalize(normalize(z @ Dp) + mean), z = relu(s) ---
    kg1f<1><<<512, 512, 0, stream>>>(SH, SL, DHs, DLs, Qp);
    kredf<0><<<BDIM * DM / 1024, 256, 0, stream>>>(Qp, nullptr, aD, nullptr, nullptr);
    kfinal<<<BDIM, 256, 0, stream>>>(aD, mean, out);
}

// Round 5
// 9523.808 us; speedup vs baseline: 1.4957x; 1.1900x over previous
//
#include <hip/hip_runtime.h>
#include <cstddef>
#include <cstdint>

// Problem constants
#define BDIM  1024        // batch rows
#define DM    512         // embedding dim
#define CREAL 10000       // dictionary atoms
#define CP    10112       // padded atoms = 79*128 = 316*32
#define KSPL  16          // split-K chunks for GEMM1
#define RHOC  5.0f
#define THRC  (0.01f/5.0f)
#define NIT   100
#define NSIT  12

typedef float f32x4 __attribute__((ext_vector_type(4)));
typedef _Float16 f16x8 __attribute__((ext_vector_type(8)));
typedef _Float16 f16x4 __attribute__((ext_vector_type(4)));
typedef unsigned int u32x4 __attribute__((ext_vector_type(4)));

// ---------------- helpers ----------------

// Pair scheme: x ~ h + l/64, h=fp16(x), l=fp16((x-h)*64). GEMM uses 3 terms:
// h*h + (h*2^-6)*l + l*(h*2^-6)  (l*l dropped, ~2^-24 rel).
__device__ __forceinline__ f16x8 scl6(f16x8 v) {
    f16x8 r;
#pragma unroll
    for (int i = 0; i < 8; i++) r[i] = v[i] * (_Float16)0.015625f;  // exact exponent shift
    return r;
}

// |s| on an (h,l) pair is EXACT: flip both signs where h is negative.
__device__ __forceinline__ void absfold(f16x8& h8, f16x8& l8) {
    u32x4 h = __builtin_bit_cast(u32x4, h8);
    u32x4 l = __builtin_bit_cast(u32x4, l8);
    u32x4 m = h & 0x80008000u;
    h8 = __builtin_bit_cast(f16x8, h ^ m);
    l8 = __builtin_bit_cast(f16x8, l ^ m);
}

// relu(s) on an (h,l) pair: zero both where h<=0 (edge err ~2^-24, negligible).
__device__ __forceinline__ void relufold(f16x8& h8, f16x8& l8) {
#pragma unroll
    for (int e = 0; e < 8; e++) {
        bool p = h8[e] > (_Float16)0;
        if (!p) { h8[e] = (_Float16)0; l8[e] = (_Float16)0; }
    }
}

// fragment-swizzled plane index for an A-operand matrix [rows][C]:
//   idx = ((row>>4)*(C>>5) + (col>>5))*512 + (((col>>3)&3)*16 + (row&15))*8 + (col&7)
// so a wave's fragment load for (rowtile, coltile32) is base + lane*8.
__device__ __forceinline__ size_t psidx(int row, int col) {   // C = CP (s-planes)
    return ((size_t)(row >> 4) * (CP >> 5) + (size_t)(col >> 5)) * 512
         + (size_t)((((col >> 3) & 3) * 16 + (row & 15)) * 8 + (col & 7));
}

// async 16B-per-lane global -> LDS DMA (no VGPR transit). LDS dest is the
// WAVE-UNIFORM base; HW adds lane*16. Global src is per-lane.
__device__ __forceinline__ void dma16(const _Float16* g, _Float16* l) {
    __builtin_amdgcn_global_load_lds(
        (const __attribute__((address_space(1))) void*)g,
        (__attribute__((address_space(3))) void*)l, 16, 0, 0);
}

__device__ __forceinline__ float blk_sum256(float v) {
    __shared__ float sb[4];
#pragma unroll
    for (int o = 32; o; o >>= 1) v += __shfl_down(v, o, 64);
    int lane = threadIdx.x & 63, w = threadIdx.x >> 6;
    __syncthreads();
    if (lane == 0) sb[w] = v;
    __syncthreads();
    return sb[0] + sb[1] + sb[2] + sb[3];
}

// txt = normalize(text) per row
__global__ __launch_bounds__(256) void knorm_rows(const float* __restrict__ X,
                                                  float* __restrict__ out) {
    int row = blockIdx.x, t = threadIdx.x;
    int off = row * DM + t * 2;
    float2 v = *(const float2*)(X + off);
    float ss = blk_sum256(v.x * v.x + v.y * v.y);
    float inv = 1.0f / fmaxf(sqrtf(ss), 1e-12f);
    float2 o = {v.x * inv, v.y * inv};
    *(float2*)(out + off) = o;
}

// Y = normalize(normalize(image) - mean) per row
__global__ __launch_bounds__(256) void kprep_Y(const float* __restrict__ img,
                                               const float* __restrict__ mean,
                                               float* __restrict__ Y) {
    int row = blockIdx.x, t = threadIdx.x;
    int off = row * DM + t * 2;
    float2 v = *(const float2*)(img + off);
    float ss = blk_sum256(v.x * v.x + v.y * v.y);
    float inv = 1.0f / fmaxf(sqrtf(ss), 1e-12f);
    float2 mm = *(const float2*)(mean + t * 2);
    float tx = v.x * inv - mm.x, ty = v.y * inv - mm.y;
    float ss2 = blk_sum256(tx * tx + ty * ty);
    float inv2 = 1.0f / fmaxf(sqrtf(ss2), 1e-12f);
    float2 o = {tx * inv2, ty * inv2};
    *(float2*)(Y + off) = o;
}

// transpose (+zero-pad rows>=Rvalid), split to fp16 h/l pair (l stored *64) and write
// the fp16 planes in MFMA FRAGMENT-SWIZZLED order (see psidx formula).
// optional fp32 out = reconstructed pair, ROW-MAJOR.
__global__ __launch_bounds__(256) void ktrs(const float* __restrict__ in,
                                            float* __restrict__ out32,
                                            _Float16* __restrict__ oH,
                                            _Float16* __restrict__ oL,
                                            int Rvalid, int Cin, int Rout) {
    __shared__ float tile[64][65];
    int r0 = blockIdx.x * 64;   // rows of in  (cols of out)
    int c0 = blockIdx.y * 64;   // cols of in  (rows of out)
    int t = threadIdx.x;
    int ri = r0 + (t >> 2);
    int cc = (t & 3) * 16;
#pragma unroll
    for (int q = 0; q < 4; ++q) {
        float4 v = {0.f, 0.f, 0.f, 0.f};
        if (ri < Rvalid) v = *(const float4*)(in + (size_t)ri * Cin + c0 + cc + q * 4);
        *(float4*)&tile[t >> 2][cc + q * 4] = v;
    }
    __syncthreads();
    int oc = c0 + (t >> 2);            // out row
    int orr = r0 + (t & 3) * 16;       // out col base (multiple of 16)
    _Float16 hv[16], lv[16];
#pragma unroll
    for (int q = 0; q < 16; ++q) {
        float v = tile[(t & 3) * 16 + q][t >> 2];
        _Float16 h = (_Float16)v;
        _Float16 l = (_Float16)((v - (float)h) * 64.f);
        hv[q] = h; lv[q] = l;
        if (out32) out32[(size_t)oc * Rout + orr + q] = (float)h + (float)l * 0.015625f;
    }
    int rt = oc >> 4, rin = oc & 15;
    int kt = orr >> 5;
    int kq0 = (orr >> 3) & 3;          // 0 or 2
    size_t base = ((size_t)rt * (Rout >> 5) + kt) * 512;
    *(f16x8*)(oH + base + (size_t)(kq0 * 16 + rin) * 8)       = *(f16x8*)&hv[0];
    *(f16x8*)(oH + base + (size_t)((kq0 + 1) * 16 + rin) * 8) = *(f16x8*)&hv[8];
    *(f16x8*)(oL + base + (size_t)(kq0 * 16 + rin) * 8)       = *(f16x8*)&lv[0];
    *(f16x8*)(oL + base + (size_t)((kq0 + 1) * 16 + rin) * 8) = *(f16x8*)&lv[8];
}

// csum[n] = sum_k Dt[n][k]  (deterministic per-row wave reduce)
__global__ void kcsum(const float* __restrict__ Dt, float* __restrict__ csum) {
    int n = blockIdx.x, t = threadIdx.x;   // 64 threads = 1 wave
    float s = 0.f;
    for (int k = t; k < CP; k += 64) s += Dt[(size_t)n * CP + k];
#pragma unroll
    for (int o = 32; o; o >>= 1) s += __shfl_down(s, o, 64);
    if (t == 0) csum[n] = s;
}

// G = Dt*Dt^T + rho I  (Dt [512][CP] fp32; 64x64 tiles, K=CP)
__global__ __launch_bounds__(256) void kG(const float* __restrict__ Dt,
                                          float* __restrict__ G) {
    __shared__ float As[32][68];
    __shared__ float Bs[32][68];
    int tid = threadIdx.x;
    int j0 = blockIdx.x * 64, i0 = blockIdx.y * 64;
    int tn = (tid & 15) * 4, tm = (tid >> 4) * 4;
    float acc[4][4];
#pragma unroll
    for (int i = 0; i < 4; i++)
#pragma unroll
        for (int j = 0; j < 4; j++) acc[i][j] = 0.f;
    for (int k0 = 0; k0 < CP; k0 += 32) {
        __syncthreads();
#pragma unroll
        for (int p = 0; p < 2; ++p) {
            int idx = tid + p * 256;
            int row = idx >> 3, kv = (idx & 7) << 2;
            float4 va = *(const float4*)(Dt + (size_t)(i0 + row) * CP + k0 + kv);
            As[kv + 0][row] = va.x; As[kv + 1][row] = va.y;
            As[kv + 2][row] = va.z; As[kv + 3][row] = va.w;
            float4 vb = *(const float4*)(Dt + (size_t)(j0 + row) * CP + k0 + kv);
            Bs[kv + 0][row] = vb.x; Bs[kv + 1][row] = vb.y;
            Bs[kv + 2][row] = vb.z; Bs[kv + 3][row] = vb.w;
        }
        __syncthreads();
#pragma unroll
        for (int k = 0; k < 32; ++k) {
            float4 a4 = *(const float4*)&As[k][tm];
            float4 b4 = *(const float4*)&Bs[k][tn];
            float af[4] = {a4.x, a4.y, a4.z, a4.w};
            float bf[4] = {b4.x, b4.y, b4.z, b4.w};
#pragma unroll
            for (int i = 0; i < 4; i++)
#pragma unroll
                for (int j = 0; j < 4; j++) acc[i][j] = fmaf(af[i], bf[j], acc[i][j]);
        }
    }
#pragma unroll
    for (int i = 0; i < 4; i++)
#pragma unroll
        for (int j = 0; j < 4; j++) {
            int gi = i0 + tm + i, gj = j0 + tn + j;
            G[gi * DM + gj] = acc[i][j] + ((gi == gj) ? RHOC : 0.f);
        }
}

__global__ void krow_abssum(const float* __restrict__ G, float* __restrict__ gmax) {
    int row = blockIdx.x, t = threadIdx.x;   // 64 threads = 1 wave
    float s = 0.f;
    for (int j = t; j < DM; j += 64) s += fabsf(G[row * DM + j]);
#pragma unroll
    for (int o = 32; o; o >>= 1) s += __shfl_down(s, o, 64);
    if (t == 0) atomicMax((int*)gmax, __float_as_int(s));
}

__global__ void kinit_X0(const float* __restrict__ gmax, float* __restrict__ X) {
    int idx = blockIdx.x * 256 + threadIdx.x;
    int i = idx >> 9, j = idx & 511;
    X[idx] = (i == j) ? (1.0f / gmax[0]) : 0.0f;
}

// T = G @ X (512^3 NN, 64x64 tiles)
__global__ __launch_bounds__(256) void kgemm_ns_T(const float* __restrict__ G,
                                                  const float* __restrict__ X,
                                                  float* __restrict__ T) {
    __shared__ float As[32][68];
    __shared__ float Bs[32][68];
    int tid = threadIdx.x;
    int n0 = blockIdx.x * 64, m0 = blockIdx.y * 64;
    int tn = (tid & 15) * 4, tm = (tid >> 4) * 4;
    float acc[4][4];
#pragma unroll
    for (int i = 0; i < 4; i++)
#pragma unroll
        for (int j = 0; j < 4; j++) acc[i][j] = 0.f;
    for (int k0 = 0; k0 < DM; k0 += 32) {
        __syncthreads();
#pragma unroll
        for (int p = 0; p < 2; ++p) {
            int idx = tid + p * 256;
            {
                int row = idx >> 3, kv = (idx & 7) << 2;
                float4 v = *(const float4*)(G + (m0 + row) * DM + k0 + kv);
                As[kv + 0][row] = v.x; As[kv + 1][row] = v.y;
                As[kv + 2][row] = v.z; As[kv + 3][row] = v.w;
            }
            {
                int r = idx >> 4, cv = (idx & 15) << 2;
                *(float4*)&Bs[r][cv] = *(const float4*)(X + (k0 + r) * DM + n0 + cv);
            }
        }
        __syncthreads();
#pragma unroll
        for (int k = 0; k < 32; ++k) {
            float4 a4 = *(const float4*)&As[k][tm];
            float4 b4 = *(const float4*)&Bs[k][tn];
            float af[4] = {a4.x, a4.y, a4.z, a4.w};
            float bf[4] = {b4.x, b4.y, b4.z, b4.w};
#pragma unroll
            for (int i = 0; i < 4; i++)
#pragma unroll
                for (int j = 0; j < 4; j++) acc[i][j] = fmaf(af[i], bf[j], acc[i][j]);
        }
    }
#pragma unroll
    for (int i = 0; i < 4; i++) {
        float4 o = {acc[i][0], acc[i][1], acc[i][2], acc[i][3]};
        *(float4*)(T + (m0 + tm + i) * DM + n0 + tn) = o;
    }
}

// Xn = 2*Xo - Xo @ T
__global__ __launch_bounds__(256) void kgemm_ns_X(const float* __restrict__ Xo,
                                                  const float* __restrict__ T,
                                                  float* __restrict__ Xn) {
    __shared__ float As[32][68];
    __shared__ float Bs[32][68];
    int tid = threadIdx.x;
    int n0 = blockIdx.x * 64, m0 = blockIdx.y * 64;
    int tn = (tid & 15) * 4, tm = (tid >> 4) * 4;
    float acc[4][4];
#pragma unroll
    for (int i = 0; i < 4; i++)
#pragma unroll
        for (int j = 0; j < 4; j++) acc[i][j] = 0.f;
    for (int k0 = 0; k0 < DM; k0 += 32) {
        __syncthreads();
#pragma unroll
        for (int p = 0; p < 2; ++p) {
            int idx = tid + p * 256;
            {
                int row = idx >> 3, kv = (idx & 7) << 2;
                float4 v = *(const float4*)(Xo + (m0 + row) * DM + k0 + kv);
                As[kv + 0][row] = v.x; As[kv + 1][row] = v.y;
                As[kv + 2][row] = v.z; As[kv + 3][row] = v.w;
            }
            {
                int r = idx >> 4, cv = (idx & 15) << 2;
                *(float4*)&Bs[r][cv] = *(const float4*)(T + (k0 + r) * DM + n0 + cv);
            }
        }
        __syncthreads();
#pragma unroll
        for (int k = 0; k < 32; ++k) {
            float4 a4 = *(const float4*)&As[k][tm];
            float4 b4 = *(const float4*)&Bs[k][tn];
            float af[4] = {a4.x, a4.y, a4.z, a4.w};
            float bf[4] = {b4.x, b4.y, b4.z, b4.w};
#pragma unroll
            for (int i = 0; i < 4; i++)
#pragma unroll
                for (int j = 0; j < 4; j++) acc[i][j] = fmaf(af[i], bf[j], acc[i][j]);
        }
    }
#pragma unroll
    for (int i = 0; i < 4; i++) {
        int base = (m0 + tm + i) * DM + n0 + tn;
        float4 xo = *(const float4*)(Xo + base);
        float4 o = {2.f * xo.x - acc[i][0], 2.f * xo.y - acc[i][1],
                    2.f * xo.z - acc[i][2], 2.f * xo.w - acc[i][3]};
        *(float4*)(Xn + base) = o;
    }
}

// NN fp32: out[M][CP] = A[M][512] @ B[512][CP]
// MODE 0: store fp32. MODE 1: store a = acc*0.2 as fp16 scaled by 64, in the
// FRAGMENT-SWIZZLED ps-plane layout (so kg2f's epilogue reads it as f16x8).
template <int MODE>
__global__ __launch_bounds__(256) void kgemm_nn64(const float* __restrict__ A,
                                                  const float* __restrict__ B,
                                                  float* __restrict__ out32,
                                                  _Float16* __restrict__ oA) {
    __shared__ float As[32][68];
    __shared__ float Bs[32][68];
    int tid = threadIdx.x;
    int n0 = blockIdx.x * 64, m0 = blockIdx.y * 64;
    int tn = (tid & 15) * 4, tm = (tid >> 4) * 4;
    float acc[4][4];
#pragma unroll
    for (int i = 0; i < 4; i++)
#pragma unroll
        for (int j = 0; j < 4; j++) acc[i][j] = 0.f;
    for (int k0 = 0; k0 < DM; k0 += 32) {
        __syncthreads();
#pragma unroll
        for (int p = 0; p < 2; ++p) {
            int idx = tid + p * 256;
            {
                int row = idx >> 3, kv = (idx & 7) << 2;
                float4 v = *(const float4*)(A + (size_t)(m0 + row) * DM + k0 + kv);
                As[kv + 0][row] = v.x; As[kv + 1][row] = v.y;
                As[kv + 2][row] = v.z; As[kv + 3][row] = v.w;
            }
            {
                int r = idx >> 4, cv = (idx & 15) << 2;
                *(float4*)&Bs[r][cv] = *(const float4*)(B + (size_t)(k0 + r) * CP + n0 + cv);
            }
        }
        __syncthreads();
#pragma unroll
        for (int k = 0; k < 32; ++k) {
            float4 a4 = *(const float4*)&As[k][tm];
            float4 b4 = *(const float4*)&Bs[k][tn];
            float af[4] = {a4.x, a4.y, a4.z, a4.w};
            float bf[4] = {b4.x, b4.y, b4.z, b4.w};
#pragma unroll
            for (int i = 0; i < 4; i++)
#pragma unroll
                for (int j = 0; j < 4; j++) acc[i][j] = fmaf(af[i], bf[j], acc[i][j]);
        }
    }
#pragma unroll
    for (int i = 0; i < 4; i++)
#pragma unroll
        for (int j = 0; j < 4; j++) {
            int row = m0 + tm + i, col = n0 + tn + j;
            if (MODE == 0) out32[(size_t)row * CP + col] = acc[i][j];
            else           oA[psidx(row, col)] = (_Float16)(acc[i][j] * 0.2f * 64.f);
        }
}

// aD = Y@G/rho - Y - thr*csum   (out [1024][512]; 64x64 tiles, K=512)
// the -thr*csum term folds GEMM1's constant correction: v = |s| - thr.
__global__ __launch_bounds__(256) void kgemm_aD(const float* __restrict__ Yb,
                                                const float* __restrict__ G,
                                                const float* __restrict__ csum,
                                                float* __restrict__ aD) {
    __shared__ float As[32][68];
    __shared__ float Bs[32][68];
    int tid = threadIdx.x;
    int n0 = blockIdx.x * 64, m0 = blockIdx.y * 64;
    int tn = (tid & 15) * 4, tm = (tid >> 4) * 4;
    float acc[4][4];
#pragma unroll
    for (int i = 0; i < 4; i++)
#pragma unroll
        for (int j = 0; j < 4; j++) acc[i][j] = 0.f;
    for (int k0 = 0; k0 < DM; k0 += 32) {
        __syncthreads();
#pragma unroll
        for (int p = 0; p < 2; ++p) {
            int idx = tid + p * 256;
            {
                int row = idx >> 3, kv = (idx & 7) << 2;
                float4 v = *(const float4*)(Yb + (size_t)(m0 + row) * DM + k0 + kv);
                As[kv + 0][row] = v.x; As[kv + 1][row] = v.y;
                As[kv + 2][row] = v.z; As[kv + 3][row] = v.w;
            }
            {
                int r = idx >> 4, cv = (idx & 15) << 2;
                *(float4*)&Bs[r][cv] = *(const float4*)(G + (k0 + r) * DM + n0 + cv);
            }
        }
        __syncthreads();
#pragma unroll
        for (int k = 0; k < 32; ++k) {
            float4 a4 = *(const float4*)&As[k][tm];
            float4 b4 = *(const float4*)&Bs[k][tn];
            float af[4] = {a4.x, a4.y, a4.z, a4.w};
            float bf[4] = {b4.x, b4.y, b4.z, b4.w};
#pragma unroll
            for (int i = 0; i < 4; i++)
#pragma unroll
                for (int j = 0; j < 4; j++) acc[i][j] = fmaf(af[i], bf[j], acc[i][j]);
        }
    }
    float4 c4 = *(const float4*)(csum + n0 + tn);
#pragma unroll
    for (int i = 0; i < 4; i++) {
        int base = (m0 + tm + i) * DM + n0 + tn;
        float4 y4 = *(const float4*)(Yb + base);
        float4 o = {acc[i][0] * 0.2f - y4.x - THRC * c4.x,
                    acc[i][1] * 0.2f - y4.y - THRC * c4.y,
                    acc[i][2] * 0.2f - y4.z - THRC * c4.z,
                    acc[i][3] * 0.2f - y4.w - THRC * c4.w};
        *(float4*)(aD + base) = o;
    }
}

// fill s-planes with the pair of (-thr): s0 = P0 - thr = -thr  (P0 = 0)
__global__ void kinit_s(_Float16* __restrict__ SHp, _Float16* __restrict__ SLp) {
    size_t i = ((size_t)blockIdx.x * 256 + threadIdx.x) * 8;
    _Float16 h = (_Float16)(-THRC);
    _Float16 l = (_Float16)((-THRC - (float)h) * 64.f);
    f16x8 hv, lv;
#pragma unroll
    for (int e = 0; e < 8; e++) { hv[e] = h; lv[e] = l; }
    *(f16x8*)(SHp + i) = hv;
    *(f16x8*)(SLp + i) = lv;
}

// ------- loop kernels: 8-wave blocks, BOTH operands DMA-staged (LDS dbuf) -------
// LDS buf layout (32 KB): A chunks c=0..15 at c*512 halfs (tile t=c>>1, plane c&1),
// B chunks at 8192 + (t*2+p)*512. All fragment-linear -> DMA dest linear,
// ds_read = lane*16B (conflict-free).

__device__ __forceinline__ void stage2(_Float16* __restrict__ sab,
                                       const _Float16* __restrict__ AHp,
                                       const _Float16* __restrict__ ALp,
                                       const _Float16* __restrict__ BHp,
                                       const _Float16* __restrict__ BLp,
                                       int sp, int mtbB, int ntbB, int ktA, int ktB,
                                       int wvu, int lane) {
#pragma unroll
    for (int k = 0; k < 4; ++k) {
        const int c = wvu * 4 + k;       // 0..31 (A: 0..15, B: 16..31); wave-uniform side
        const int t = (c >> 1) & 7;
        const int p = c & 1;
        const _Float16* gp;
        if (c < 16) gp = (p ? ALp : AHp) + ((size_t)(mtbB + t) * ktA + sp) * 512 + (size_t)lane * 8;
        else        gp = (p ? BLp : BHp) + ((size_t)(ntbB + t) * ktB + sp) * 512 + (size_t)lane * 8;
        dma16(gp, sab + (size_t)c * 512);
    }
}

// 24-MFMA cluster for a 64x32 wave tile. FOLD: 0=abs, 1=relu, 2=none.
template <int FOLD>
__device__ __forceinline__ void compute8(const _Float16* __restrict__ sab,
                                         int wm, int wn, int lane,
                                         f32x4 (&acc)[4][2]) {
    const int ta = wm >> 4;      // 0 or 4
    const int tb = wn >> 4;      // 0,2,4,6
    f16x8 bh[2], bl[2], bs_[2];
#pragma unroll
    for (int j = 0; j < 2; ++j) {
        const _Float16* p = sab + 8192 + (size_t)(tb + j) * 1024 + (size_t)lane * 8;
        bh[j] = *(const f16x8*)p;
        bl[j] = *(const f16x8*)(p + 512);
        bs_[j] = scl6(bh[j]);
    }
    f16x8 ah[4], al[4], as_[4];
#pragma unroll
    for (int i = 0; i < 4; ++i) {
        const _Float16* p = sab + (size_t)(ta + i) * 1024 + (size_t)lane * 8;
        ah[i] = *(const f16x8*)p;
        al[i] = *(const f16x8*)(p + 512);
    }
#pragma unroll
    for (int i = 0; i < 4; ++i) {
        if (FOLD == 0) absfold(ah[i], al[i]);
        else if (FOLD == 1) relufold(ah[i], al[i]);
        as_[i] = scl6(ah[i]);
    }
    __builtin_amdgcn_s_setprio(1);
#pragma unroll
    for (int i = 0; i < 4; ++i)
#pragma unroll
        for (int j = 0; j < 2; ++j) {
            acc[i][j] = __builtin_amdgcn_mfma_f32_16x16x32_f16(ah[i],  bh[j], acc[i][j], 0, 0, 0);
            acc[i][j] = __builtin_amdgcn_mfma_f32_16x16x32_f16(as_[i], bl[j], acc[i][j], 0, 0, 0);
            acc[i][j] = __builtin_amdgcn_mfma_f32_16x16x32_f16(al[i],  bs_[j], acc[i][j], 0, 0, 0);
        }
    __builtin_amdgcn_s_setprio(0);
}

// GEMM1 partial: Qp[ks] = op(s) @ Dp over this ks's K-chunk of CP.
// MODE 0 (loop): op = |s|; MODE 1 (final): op = relu(s).
// 512 blocks x 512 thr (8 waves, 2M x 4N of 64x32 tiles) = exactly 2 blocks/CU.
template <int MODE>
__global__ __launch_bounds__(512, 4) void kg1f(const _Float16* __restrict__ SHp,
                                               const _Float16* __restrict__ SLp,
                                               const _Float16* __restrict__ DHs,
                                               const _Float16* __restrict__ DLs,
                                               float* __restrict__ Qp) {
    __shared__ _Float16 sAB[2][16384];   // 2 x 32 KB
    const int raw = blockIdx.x;
    const int xcd = raw & 7;
    const int r   = raw >> 3;            // 0..63
    const int ks  = xcd * 2 + (r & 1);   // 0..15
    const int q   = r >> 1;              // 0..31
    const int mb  = q >> 2, nb = q & 3;
    const int n0 = nb * 128, m0 = mb * 128;
    const int tid = threadIdx.x;
    const int lane = tid & 63;
    const int wvu = tid >> 6;            // 0..7
    const int wm = (wvu >> 2) * 64;      // 0,64
    const int wn = (wvu & 3) * 32;       // 0,32,64,96
    f32x4 acc[4][2] = {};

    const int steps = CP / 32;                    // 316
    const int per = (steps + KSPL - 1) / KSPL;    // 20
    int s0 = ks * per;
    int s1 = s0 + per; if (s1 > steps) s1 = steps;

    const int mtbB = m0 >> 4;
    const int ntbB = n0 >> 4;
    const int KT = CP / 32;

    stage2(sAB[0], SHp, SLp, DHs, DLs, s0, mtbB, ntbB, KT, KT, wvu, lane);
    __syncthreads();

    for (int sp = s0; sp < s1; sp += 2) {
        stage2(sAB[1], SHp, SLp, DHs, DLs, sp + 1, mtbB, ntbB, KT, KT, wvu, lane);
        compute8<MODE>(sAB[0], wm, wn, lane, acc);
        __syncthreads();
        if (sp + 2 < s1)
            stage2(sAB[0], SHp, SLp, DHs, DLs, sp + 2, mtbB, ntbB, KT, KT, wvu, lane);
        compute8<MODE>(sAB[1], wm, wn, lane, acc);
        __syncthreads();
    }

    float* outp = Qp + (size_t)ks * (BDIM * DM);
    const int r0 = (lane >> 4) * 4, c0l = lane & 15;
#pragma unroll
    for (int i = 0; i < 4; i++)
#pragma unroll
        for (int v = 0; v < 4; v++) {
            int row = m0 + wm + i * 16 + r0 + v;
#pragma unroll
            for (int j = 0; j < 2; j++)
                outp[(size_t)row * DM + n0 + wn + j * 16 + c0l] = acc[i][j][v];
        }
}

// Qf reduce: ADD=1 (loop): Qf = aD' + sum Qp -> write Qf h/l FRAGMENT PLANES.
//            ADD=0 (final): Qf = sum Qp -> write fp32 row-major to out32.
template <int ADD>
__global__ void kredf(const float* __restrict__ Qp, const float* __restrict__ aD,
                      float* __restrict__ out32, _Float16* __restrict__ QH,
                      _Float16* __restrict__ QL) {
    size_t b = ((size_t)blockIdx.x * 256 + threadIdx.x) * 4;
    float4 s = {0.f, 0.f, 0.f, 0.f};
    if (ADD) s = *(const float4*)(aD + b);
#pragma unroll
    for (int qq = 0; qq < KSPL; qq++) {
        float4 t = *(const float4*)(Qp + (size_t)qq * (BDIM * DM) + b);
        s.x += t.x; s.y += t.y; s.z += t.z; s.w += t.w;
    }
    if (ADD) {
        int row = (int)(b >> 9), col = (int)(b & 511);
        size_t t0 = ((size_t)(row >> 4) * 16 + (size_t)(col >> 5)) * 512
                  + (size_t)((((col >> 3) & 3) * 16 + (row & 15)) * 8 + (col & 7));
        float sv[4] = {s.x, s.y, s.z, s.w};
        f16x4 h4, l4;
#pragma unroll
        for (int e = 0; e < 4; e++) {
            _Float16 h = (_Float16)sv[e];
            h4[e] = h;
            l4[e] = (_Float16)((sv[e] - (float)h) * 64.f);
        }
        *(f16x4*)(QH + t0) = h4;
        *(f16x4*)(QL + t0) = l4;
    } else {
        *(float4*)(out32 + b) = s;
    }
}

// GEMM2: acc = Qf @ E^T (out [1024][CP], K=512), fused ADMM epilogue on s-planes:
//   s_old -> z = relu(s_old); P_new = a + z - acc; s_new = P_new - thr (pair stores).
// 8-wave blocks, both operands DMA-staged. 16 even k-steps.
// Epilogue: acc is transposed through a WAVE-PRIVATE LDS region (stride 36:
// conflict-free scalar writes; float4 reads at the structural LDS floor) so each
// lane owns 8 consecutive elements of the fragment plane -> all state RMW is
// f16x8 vector loads/stores at base + lane*8 (coalesced 1 KB/wave).
__global__ __launch_bounds__(512, 4) void kg2f(const _Float16* __restrict__ QH,
                                               const _Float16* __restrict__ QL,
                                               const _Float16* __restrict__ EHs,
                                               const _Float16* __restrict__ ELs,
                                               const _Float16* __restrict__ AH,
                                               _Float16* __restrict__ SHp,
                                               _Float16* __restrict__ SLp) {
    __shared__ _Float16 sAB[2][16384];
    const int raw = blockIdx.x;
    const int g = raw & 7;
    const int q = raw >> 3;              // 0..79
    const int mb = q & 7, jj = q >> 3;   // jj 0..9
    const int nb = g * 10 + jj;
    if (nb >= 79) return;
    const int n0 = nb * 128, m0 = mb * 128;
    const int tid = threadIdx.x;
    const int lane = tid & 63;
    const int wvu = tid >> 6;
    const int wm = (wvu >> 2) * 64;
    const int wn = (wvu & 3) * 32;
    const int mtbB = m0 >> 4;
    const int ntbB = n0 >> 4;
    const int KT = DM / 32;              // 16
    f32x4 acc[4][2] = {};

    stage2(sAB[0], QH, QL, EHs, ELs, 0, mtbB, ntbB, KT, KT, wvu, lane);
    __syncthreads();

    for (int kk = 0; kk < KT; kk += 2) {
        stage2(sAB[1], QH, QL, EHs, ELs, kk + 1, mtbB, ntbB, KT, KT, wvu, lane);
        compute8<2>(sAB[0], wm, wn, lane, acc);
        __syncthreads();
        if (kk + 2 < KT)
            stage2(sAB[0], QH, QL, EHs, ELs, kk + 2, mtbB, ntbB, KT, KT, wvu, lane);
        compute8<2>(sAB[1], wm, wn, lane, acc);
        __syncthreads();
    }

    // ---- fused epilogue (vectorized via wave-private LDS transpose) ----
    const int r0 = (lane >> 4) * 4, c0l = lane & 15;
    const int mtbA = (m0 + wm) >> 4;     // wave's A row-tile base
    const int ktb  = (n0 + wn) >> 5;     // wave's 32-col tile index
#pragma unroll
    for (int i = 0; i < 4; ++i) {
        float* sT = (float*)(&sAB[i & 1][0]) + wvu * (16 * 36);
#pragma unroll
        for (int j = 0; j < 2; ++j)
#pragma unroll
            for (int v = 0; v < 4; ++v)
                sT[(r0 + v) * 36 + j * 16 + c0l] = acc[i][j][v];
        float e[8];
        *(float4*)&e[0] = *(const float4*)&sT[(lane & 15) * 36 + (lane >> 4) * 8];
        *(float4*)&e[4] = *(const float4*)&sT[(lane & 15) * 36 + (lane >> 4) * 8 + 4];
        size_t base = ((size_t)(mtbA + i) * (CP >> 5) + ktb) * 512 + (size_t)lane * 8;
        f16x8 ah8 = *(const f16x8*)(AH + base);
        f16x8 sh8 = *(const f16x8*)(SHp + base);
        f16x8 sl8 = *(const f16x8*)(SLp + base);
        f16x8 nh, nl;
#pragma unroll
        for (int e8 = 0; e8 < 8; ++e8) {
            float a = (float)ah8[e8] * 0.015625f;
            float sold = (float)sh8[e8] + (float)sl8[e8] * 0.015625f;
            float z = fmaxf(sold, 0.f);
            float pn = a + z - e[e8];
            float sn = pn - THRC;
            _Float16 h = (_Float16)sn;
            nh[e8] = h;
            nl[e8] = (_Float16)((sn - (float)h) * 64.f);
        }
        *(f16x8*)(SHp + base) = nh;
        *(f16x8*)(SLp + base) = nl;
    }
}

// final: recon = normalize(normalize(Qf) + mean)
__global__ __launch_bounds__(256) void kfinal(const float* __restrict__ Qf,
                                              const float* __restrict__ mean,
                                              float* __restrict__ out) {
    int row = blockIdx.x, t = threadIdx.x;
    int off = row * DM + t * 2;
    float2 qv = *(const float2*)(Qf + off);
    float rx = qv.x, ry = qv.y;
    float ss = blk_sum256(rx * rx + ry * ry);
    float inv = 1.0f / fmaxf(sqrtf(ss), 1e-12f);
    rx *= inv; ry *= inv;
    float2 mm = *(const float2*)(mean + t * 2);
    rx += mm.x; ry += mm.y;
    float ss2 = blk_sum256(rx * rx + ry * ry);
    float inv2 = 1.0f / fmaxf(sqrtf(ss2), 1e-12f);
    float2 o = {rx * inv2, ry * inv2};
    *(float2*)(out + off) = o;
}

extern "C" void kernel_launch(void* const* d_in, const int* in_sizes, int n_in,
                              void* d_out, int out_size, void* d_ws, size_t ws_size,
                              hipStream_t stream) {
    const float* image = (const float*)d_in[0];
    const float* text  = (const float*)d_in[1];
    const float* mean  = (const float*)d_in[2];
    const float* D     = (const float*)d_in[3];
    float* out = (float*)d_out;
    float* ws = (float*)d_ws;

    // ---- workspace layout (float offsets); total 35,324,480 floats = 141.3 MB ----
    const size_t PLH = (size_t)DM * CP;                 // halfs per D/E plane
    float* aD   = ws;                                   // [1024][512] (also final Qf32)
    _Float16* QH = (_Float16*)(ws + 524288);            // Qf h-plane (frag-swizzled)
    _Float16* QL = QH + (size_t)BDIM * DM;              // Qf l-plane
    _Float16* DHs = (_Float16*)(ws + 1048576);          // D planes [DM][CP]
    _Float16* DLs = DHs + PLH;
    _Float16* EHs = DLs + PLH;                          // E planes [CP][DM]
    _Float16* ELs = EHs + PLH;
    _Float16* AH  = ELs + PLH;                          // a*64 fp16 [1024][CP] ps-layout
    _Float16* SH  = AH + (size_t)BDIM * CP;             // s h-plane (frag-swizzled [1024][CP])
    _Float16* SL  = SH + (size_t)BDIM * CP;             // s l-plane
    float* Qp   = (float*)(SL + (size_t)BDIM * CP);     // KSPL x [1024][512] partials
    float* csum = Qp + (size_t)KSPL * BDIM * DM;        // 512
    float* gmax = csum + 512;                           // 64
    // setup-only aliases (dead before kinit_s fills the s-planes):
    float* Dt32 = (float*)SH;                           // [512][CP] fp32
    float* G    = Dt32 + (size_t)DM * CP;
    float* Xa   = G + 262144;
    float* Xb   = Xa + 262144;
    float* Tns  = Xb + 262144;
    float* Y    = Tns + 262144;
    float* Et32 = (float*)AH;                           // [512][CP] fp32 (pre-AH)

    // --- setup ---
    knorm_rows<<<BDIM, 256, 0, stream>>>(text, out + (size_t)BDIM * DM);
    kprep_Y<<<BDIM, 256, 0, stream>>>(image, mean, Y);
    ktrs<<<dim3(CP / 64, DM / 64), 256, 0, stream>>>(D, Dt32, DHs, DLs, CREAL, DM, CP);
    kcsum<<<DM, 64, 0, stream>>>(Dt32, csum);
    kG<<<dim3(8, 8), 256, 0, stream>>>(Dt32, G);
    (void)hipMemsetAsync(gmax, 0, 4, stream);
    krow_abssum<<<DM, 64, 0, stream>>>(G, gmax);
    kinit_X0<<<DM * DM / 256, 256, 0, stream>>>(gmax, Xa);
    float* xc = Xa;
    float* xn = Xb;
    for (int it = 0; it < NSIT; ++it) {
        kgemm_ns_T<<<dim3(8, 8), 256, 0, stream>>>(G, xc, Tns);
        kgemm_ns_X<<<dim3(8, 8), 256, 0, stream>>>(xc, Tns, xn);
        float* tmp = xc; xc = xn; xn = tmp;
    }
    float* Ginv = xc;
    kgemm_nn64<0><<<dim3(CP / 64, DM / 64), 256, 0, stream>>>(Ginv, Dt32, Et32, nullptr);
    ktrs<<<dim3(DM / 64, CP / 64), 256, 0, stream>>>(Et32, nullptr, EHs, ELs, DM, CP, DM);
    kgemm_nn64<1><<<dim3(CP / 64, BDIM / 64), 256, 0, stream>>>(Y, Dt32, nullptr, AH);
    kgemm_aD<<<dim3(DM / 64, BDIM / 64), 256, 0, stream>>>(Y, G, csum, aD);
    // s0 = -thr everywhere (P0 = 0); clobbers all setup-only aliases (now dead)
    kinit_s<<<(int)((size_t)BDIM * CP / 8 / 256), 256, 0, stream>>>(SH, SL);

    // --- ADMM main loop: 8-wave DMA-staged GEMMs at 16 waves/CU ---
    for (int it = 0; it < NIT; ++it) {
        kg1f<0><<<512, 512, 0, stream>>>(SH, SL, DHs, DLs, Qp);
        kredf<1><<<BDIM * DM / 1024, 256, 0, stream>>>(Qp, aD, nullptr, QH, QL);
        kg2f<<<640, 512, 0, stream>>>(QH, QL, EHs, ELs, AH, SH, SL);
    }

    // --- finalize: recon = normalize(normalize(z @ Dp) + mean), z = relu(s) ---
    kg1f<1><<<512, 512, 0, stream>>>(SH, SL, DHs, DLs, Qp);
    kredf<0><<<BDIM * DM / 1024, 256, 0, stream>>>(Qp, nullptr, aD, nullptr, nullptr);
    kfinal<<<BDIM, 256, 0, stream>>>(aD, mean, out);
}